// Round 1
// baseline (6327.150 us; speedup 1.0000x reference)
//
#include <hip/hip_runtime.h>
#include <math.h>

// Problem constants
constexpr int BB   = 8;      // mamba batch (2x half-batch)
constexpr int HB   = 4;      // half batch
constexpr int LSEQ = 2048;   // sequence length (C in the outer view)
constexpr int DMv  = 64;     // d_model
constexpr int DIv  = 128;    // d_inner
constexpr int DSv  = 16;     // d_state
constexpr int DRv  = 4;      // dt rank
constexpr int KCv  = 4;      // conv kernel
constexpr int NPOS = BB * LSEQ;  // 16384 (b,l) positions

#define DEV static __device__ __forceinline__

DEV float siluf(float v) { return v / (1.0f + __expf(-v)); }
DEV float softplusf(float v) { return (v > 20.0f) ? v : log1pf(__expf(v)); }

// ---------------- xz = u @ in_w^T ; split into x_raw and silu(z) ----------------
__global__ void k_xz(const float* __restrict__ U, const float* __restrict__ in_w,
                     float* __restrict__ XR, float* __restrict__ SZ) {
    int idx = blockIdx.x * blockDim.x + threadIdx.x;
    if (idx >= NPOS * 2 * DIv) return;
    int e   = idx & 255;
    int pos = idx >> 8;
    const float4* u4 = (const float4*)(U + (size_t)pos * DMv);
    const float4* w4 = (const float4*)(in_w + (size_t)e * DMv);
    float acc = 0.f;
#pragma unroll
    for (int k = 0; k < DMv / 4; ++k) {
        float4 a = u4[k], b = w4[k];
        acc = fmaf(a.x, b.x, acc); acc = fmaf(a.y, b.y, acc);
        acc = fmaf(a.z, b.z, acc); acc = fmaf(a.w, b.w, acc);
    }
    if (e < DIv) XR[(size_t)pos * DIv + e] = acc;
    else         SZ[(size_t)pos * DIv + (e - DIv)] = siluf(acc);
}

// ---------------- causal depthwise conv (K=4) + silu ----------------
__global__ void k_conv(const float* __restrict__ XR, const float* __restrict__ conv_w,
                       const float* __restrict__ conv_b, float* __restrict__ XA) {
    int idx = blockIdx.x * blockDim.x + threadIdx.x;
    if (idx >= NPOS * DIv) return;
    int d   = idx & 127;
    int pos = idx >> 7;
    int b   = pos >> 11;
    int l   = pos & 2047;
    float acc = conv_b[d];
#pragma unroll
    for (int k = 0; k < KCv; ++k) {
        int l2 = l - (KCv - 1) + k;
        if (l2 >= 0)
            acc = fmaf(conv_w[d * KCv + k], XR[((size_t)((b << 11) | l2)) * DIv + d], acc);
    }
    XA[idx] = siluf(acc);
}

// ---------------- xdbl = x_act @ xp_w^T (36 outputs per position) ----------------
__global__ void k_xdbl(const float* __restrict__ XA, const float* __restrict__ xp_w,
                       float* __restrict__ XD) {
    int idx = blockIdx.x * blockDim.x + threadIdx.x;
    if (idx >= NPOS * 36) return;
    int e   = idx % 36;
    int pos = idx / 36;
    const float4* x4 = (const float4*)(XA + (size_t)pos * DIv);
    const float4* w4 = (const float4*)(xp_w + (size_t)e * DIv);
    float acc = 0.f;
#pragma unroll
    for (int k = 0; k < DIv / 4; ++k) {
        float4 a = x4[k], b = w4[k];
        acc = fmaf(a.x, b.x, acc); acc = fmaf(a.y, b.y, acc);
        acc = fmaf(a.z, b.z, acc); acc = fmaf(a.w, b.w, acc);
    }
    XD[idx] = acc;
}

// ---------------- delta = softplus(dt @ dt_w^T + dt_b) ----------------
__global__ void k_delta(const float* __restrict__ XD, const float* __restrict__ dt_w,
                        const float* __restrict__ dt_b, float* __restrict__ DL) {
    int idx = blockIdx.x * blockDim.x + threadIdx.x;
    if (idx >= NPOS * DIv) return;
    int d   = idx & 127;
    int pos = idx >> 7;
    const float* dt = XD + (size_t)pos * 36;
    float acc = dt_b[d];
#pragma unroll
    for (int r = 0; r < DRv; ++r) acc = fmaf(dt[r], dt_w[d * DRv + r], acc);
    DL[idx] = softplusf(acc);
}

// ---------------- sequential selective scan + C-dot + D*x + *silu(z) ----------------
// block: 256 threads = 16 d x 16 s.  grid: (BB, DIv/16)
__global__ void k_scan(const float* __restrict__ DL, const float* __restrict__ XA,
                       const float* __restrict__ XD, const float* __restrict__ SZ,
                       const float* __restrict__ A_log, const float* __restrict__ Dp,
                       float* __restrict__ Y) {
    int b    = blockIdx.x;
    int dblk = blockIdx.y;
    int tid  = threadIdx.x;
    int s    = tid & 15;
    int d    = dblk * 16 + (tid >> 4);
    float A  = -__expf(A_log[d * DSv + s]);
    float Dd = Dp[d];
    float h  = 0.f;
    const size_t posBase = (size_t)b * LSEQ;
    for (int l = 0; l < LSEQ; ++l) {
        size_t base = posBase + l;
        float delta = DL[base * DIv + d];
        float x     = XA[base * DIv + d];
        float Bv    = XD[base * 36 + DRv + s];
        float Cv    = XD[base * 36 + DRv + DSv + s];
        float dA    = __expf(delta * A);
        h = fmaf(dA, h, delta * Bv * x);
        float p = h * Cv;
        p += __shfl_xor(p, 1);
        p += __shfl_xor(p, 2);
        p += __shfl_xor(p, 4);
        p += __shfl_xor(p, 8);
        if (s == 0) {
            float y = p + Dd * x;
            Y[base * DIv + d] = y * SZ[base * DIv + d];
        }
    }
}

// ---------------- out = y @ out_w^T ----------------
__global__ void k_out(const float* __restrict__ Y, const float* __restrict__ out_w,
                      float* __restrict__ CF) {
    int idx = blockIdx.x * blockDim.x + threadIdx.x;
    if (idx >= NPOS * DMv) return;
    int e   = idx & 63;
    int pos = idx >> 6;
    const float4* y4 = (const float4*)(Y + (size_t)pos * DIv);
    const float4* w4 = (const float4*)(out_w + (size_t)e * DIv);
    float acc = 0.f;
#pragma unroll
    for (int k = 0; k < DIv / 4; ++k) {
        float4 a = y4[k], b = w4[k];
        acc = fmaf(a.x, b.x, acc); acc = fmaf(a.y, b.y, acc);
        acc = fmaf(a.z, b.z, acc); acc = fmaf(a.w, b.w, acc);
    }
    CF[idx] = acc;
}

// ---------------- residual combine: OUT = relu(0.5*(cf1+cf2) + RES) ----------------
__global__ void k_combine(const float* __restrict__ CF, const float* __restrict__ RES,
                          float* __restrict__ OUT) {
    int idx = blockIdx.x * blockDim.x + threadIdx.x;
    if (idx >= HB * LSEQ * DMv) return;
    float v = 0.5f * (CF[idx] + CF[idx + (size_t)HB * LSEQ * DMv]) + RES[idx];
    OUT[idx] = fmaxf(v, 0.f);
}

// ---------------- build u0 for path a: half-channel swap ----------------
__global__ void k_prep_a(const float* __restrict__ Ms, const float* __restrict__ Pan,
                         float* __restrict__ U) {
    int idx = blockIdx.x * blockDim.x + threadIdx.x;
    if (idx >= NPOS * DMv) return;
    int e   = idx & 63;
    int pos = idx >> 6;
    int c   = pos & 2047;
    int b8  = pos >> 11;
    int b   = b8 & 3;
    bool lower = c < (LSEQ / 2);
    const float* src = (b8 < HB) ? (lower ? Ms : Pan) : (lower ? Pan : Ms);
    U[idx] = src[((size_t)b * LSEQ + c) * DMv + e];
}

// ---------------- build u0 for path b: channel interleave ----------------
__global__ void k_prep_b(const float* __restrict__ Ms, const float* __restrict__ Pan,
                         float* __restrict__ U) {
    int idx = blockIdx.x * blockDim.x + threadIdx.x;
    if (idx >= NPOS * DMv) return;
    int e   = idx & 63;
    int pos = idx >> 6;
    int c   = pos & 2047;
    int b8  = pos >> 11;
    int b   = b8 & 3;
    bool even = (c & 1) == 0;
    // cf3 (b8<4): even ch from Pan, odd from Ms ; cf4 (b8>=4): opposite
    const float* src = (b8 < HB) ? (even ? Pan : Ms) : (even ? Ms : Pan);
    U[idx] = src[((size_t)b * LSEQ + c) * DMv + e];
}

extern "C" void kernel_launch(void* const* d_in, const int* in_sizes, int n_in,
                              void* d_out, int out_size, void* d_ws, size_t ws_size,
                              hipStream_t stream) {
    const float* Ms_in  = (const float*)d_in[0];
    const float* Pan_in = (const float*)d_in[1];
    const float* pa[9];
    const float* pb[9];
    for (int i = 0; i < 9; ++i) {
        pa[i] = (const float*)d_in[2 + i];
        pb[i] = (const float*)d_in[11 + i];
    }
    float* out    = (float*)d_out;
    float* OutMs  = out;                              // 4*2048*64
    float* OutPan = out + (size_t)HB * LSEQ * DMv;    // 4*2048*64

    float* ws = (float*)d_ws;
    size_t o = 0;
    float* U0 = ws + o; o += (size_t)NPOS * DMv;   // 1M floats
    float* U1 = ws + o; o += (size_t)NPOS * DMv;   // 1M
    float* XR = ws + o; o += (size_t)NPOS * DIv;   // 2M (x_raw, reused as Y)
    float* XA = ws + o; o += (size_t)NPOS * DIv;   // 2M (x after conv+silu)
    float* SZ = ws + o; o += (size_t)NPOS * DIv;   // 2M (silu(z))
    float* XD = ws + o; o += (size_t)NPOS * 36;    // 0.59M (dt|B|C)
    float* DL = ws + o; o += (size_t)NPOS * DIv;   // 2M (delta)

    const int TB = 256;
    auto mamba = [&](const float* u, float* cf, const float* const* P, int layer) {
        const float* in_w   = P[0] + (size_t)layer * 2 * DIv * DMv;
        const float* conv_w = P[1] + (size_t)layer * DIv * KCv;
        const float* conv_b = P[2] + (size_t)layer * DIv;
        const float* xp_w   = P[3] + (size_t)layer * (DRv + 2 * DSv) * DIv;
        const float* dt_w   = P[4] + (size_t)layer * DIv * DRv;
        const float* dt_b   = P[5] + (size_t)layer * DIv;
        const float* A_log  = P[6] + (size_t)layer * DIv * DSv;
        const float* Dp     = P[7] + (size_t)layer * DIv;
        const float* out_w  = P[8] + (size_t)layer * DMv * DIv;

        int n1 = NPOS * 2 * DIv;
        k_xz<<<(n1 + TB - 1) / TB, TB, 0, stream>>>(u, in_w, XR, SZ);
        int n2 = NPOS * DIv;
        k_conv<<<(n2 + TB - 1) / TB, TB, 0, stream>>>(XR, conv_w, conv_b, XA);
        int n3 = NPOS * 36;
        k_xdbl<<<(n3 + TB - 1) / TB, TB, 0, stream>>>(XA, xp_w, XD);
        k_delta<<<(n2 + TB - 1) / TB, TB, 0, stream>>>(XD, dt_w, dt_b, DL);
        dim3 g(BB, DIv / 16);
        k_scan<<<g, TB, 0, stream>>>(DL, XA, XD, SZ, A_log, Dp, XR);
        int n4 = NPOS * DMv;
        k_out<<<(n4 + TB - 1) / TB, TB, 0, stream>>>(XR, out_w, cf);
    };

    int np = NPOS * DMv;
    int nc = HB * LSEQ * DMv;

    // ---- path a (updates Ms) ----
    k_prep_a<<<(np + TB - 1) / TB, TB, 0, stream>>>(Ms_in, Pan_in, U0);
    mamba(U0, U1, pa, 0);
    k_combine<<<(nc + TB - 1) / TB, TB, 0, stream>>>(U1, Ms_in, OutMs);
    mamba(U1, U0, pa, 1);
    k_combine<<<(nc + TB - 1) / TB, TB, 0, stream>>>(U0, OutMs, OutMs);

    // ---- path b (updates Pan) ----
    k_prep_b<<<(np + TB - 1) / TB, TB, 0, stream>>>(OutMs, Pan_in, U0);
    mamba(U0, U1, pb, 0);
    k_combine<<<(nc + TB - 1) / TB, TB, 0, stream>>>(U1, Pan_in, OutPan);
    mamba(U1, U0, pb, 1);
    k_combine<<<(nc + TB - 1) / TB, TB, 0, stream>>>(U0, OutPan, OutPan);
}

// Round 2
// 1418.812 us; speedup vs baseline: 4.4595x; 4.4595x over previous
//
#include <hip/hip_runtime.h>
#include <math.h>

// Problem constants
constexpr int BB   = 8;      // mamba batch (2x half-batch)
constexpr int HB   = 4;      // half batch
constexpr int LSEQ = 2048;   // sequence length
constexpr int DMv  = 64;     // d_model
constexpr int DIv  = 128;    // d_inner
constexpr int DSv  = 16;     // d_state
constexpr int DRv  = 4;      // dt rank
constexpr int KCv  = 4;      // conv kernel
constexpr int NPOS = BB * LSEQ;          // 16384 positions
constexpr int CH   = 64;                 // scan chunk length
constexpr int NCH  = LSEQ / CH;          // 32 chunks
constexpr int NLANE = BB * DIv * DSv;    // 16384 scan lanes

#define DEV static __device__ __forceinline__

DEV float siluf(float v) { return v / (1.0f + __expf(-v)); }
DEV float softplusf(float v) { return (v > 20.0f) ? v : log1pf(__expf(v)); }

// ---------------- xz = u @ in_w^T ; split into x_raw and silu(z) ----------------
__global__ void k_xz(const float* __restrict__ U, const float* __restrict__ in_w,
                     float* __restrict__ XR, float* __restrict__ SZ) {
    int idx = blockIdx.x * blockDim.x + threadIdx.x;
    if (idx >= NPOS * 2 * DIv) return;
    int e   = idx & 255;
    int pos = idx >> 8;
    const float4* u4 = (const float4*)(U + (size_t)pos * DMv);
    const float4* w4 = (const float4*)(in_w + (size_t)e * DMv);
    float acc = 0.f;
#pragma unroll
    for (int k = 0; k < DMv / 4; ++k) {
        float4 a = u4[k], b = w4[k];
        acc = fmaf(a.x, b.x, acc); acc = fmaf(a.y, b.y, acc);
        acc = fmaf(a.z, b.z, acc); acc = fmaf(a.w, b.w, acc);
    }
    if (e < DIv) XR[(size_t)pos * DIv + e] = acc;
    else         SZ[(size_t)pos * DIv + (e - DIv)] = siluf(acc);
}

// ---------------- causal depthwise conv (K=4) + silu ----------------
__global__ void k_conv(const float* __restrict__ XR, const float* __restrict__ conv_w,
                       const float* __restrict__ conv_b, float* __restrict__ XA) {
    int idx = blockIdx.x * blockDim.x + threadIdx.x;
    if (idx >= NPOS * DIv) return;
    int d   = idx & 127;
    int pos = idx >> 7;
    int b   = pos >> 11;
    int l   = pos & 2047;
    float acc = conv_b[d];
#pragma unroll
    for (int k = 0; k < KCv; ++k) {
        int l2 = l - (KCv - 1) + k;
        if (l2 >= 0)
            acc = fmaf(conv_w[d * KCv + k], XR[((size_t)((b << 11) | l2)) * DIv + d], acc);
    }
    XA[idx] = siluf(acc);
}

// ---------------- xdbl = x_act @ xp_w^T (36 outputs per position) ----------------
__global__ void k_xdbl(const float* __restrict__ XA, const float* __restrict__ xp_w,
                       float* __restrict__ XD) {
    int idx = blockIdx.x * blockDim.x + threadIdx.x;
    if (idx >= NPOS * 36) return;
    int e   = idx % 36;
    int pos = idx / 36;
    const float4* x4 = (const float4*)(XA + (size_t)pos * DIv);
    const float4* w4 = (const float4*)(xp_w + (size_t)e * DIv);
    float acc = 0.f;
#pragma unroll
    for (int k = 0; k < DIv / 4; ++k) {
        float4 a = x4[k], b = w4[k];
        acc = fmaf(a.x, b.x, acc); acc = fmaf(a.y, b.y, acc);
        acc = fmaf(a.z, b.z, acc); acc = fmaf(a.w, b.w, acc);
    }
    XD[idx] = acc;
}

// ---------------- delta = softplus(dt @ dt_w^T + dt_b) ----------------
__global__ void k_delta(const float* __restrict__ XD, const float* __restrict__ dt_w,
                        const float* __restrict__ dt_b, float* __restrict__ DL) {
    int idx = blockIdx.x * blockDim.x + threadIdx.x;
    if (idx >= NPOS * DIv) return;
    int d   = idx & 127;
    int pos = idx >> 7;
    const float* dt = XD + (size_t)pos * 36;
    float acc = dt_b[d];
#pragma unroll
    for (int r = 0; r < DRv; ++r) acc = fmaf(dt[r], dt_w[d * DRv + r], acc);
    DL[idx] = softplusf(acc);
}

// =========== chunked parallel scan ===========
// Pass 1: per-chunk product of dA and local scan value (h starting from 0).
// grid (BB, DIv/16, NCH), block 256 = 16 d x 16 s
__global__ void k_scan1(const float* __restrict__ DL, const float* __restrict__ XA,
                        const float* __restrict__ XD, const float* __restrict__ A_log,
                        float* __restrict__ Pc, float* __restrict__ Sc) {
    int b    = blockIdx.x;
    int dblk = blockIdx.y;
    int ch   = blockIdx.z;
    int tid  = threadIdx.x;
    int s    = tid & 15;
    int d    = dblk * 16 + (tid >> 4);
    float A  = -__expf(A_log[d * DSv + s]);
    float h  = 0.f, P = 1.f;
    const size_t posBase = (size_t)b * LSEQ + (size_t)ch * CH;
    for (int l = 0; l < CH; ++l) {
        size_t base = posBase + l;
        float delta = DL[base * DIv + d];
        float x     = XA[base * DIv + d];
        float Bv    = XD[base * 36 + DRv + s];
        float dA    = __expf(delta * A);
        h = fmaf(dA, h, delta * Bv * x);
        P *= dA;
    }
    int lane = (b * DIv + d) * DSv + s;
    Pc[(size_t)ch * NLANE + lane] = P;
    Sc[(size_t)ch * NLANE + lane] = h;
}

// Pass 2: serial combine over chunks -> chunk-start states. one thread per lane.
__global__ void k_scan2(const float* __restrict__ Pc, const float* __restrict__ Sc,
                        float* __restrict__ H0) {
    int t = blockIdx.x * blockDim.x + threadIdx.x;
    if (t >= NLANE) return;
    float hs = 0.f;
#pragma unroll
    for (int c = 0; c < NCH; ++c) {
        H0[(size_t)c * NLANE + t] = hs;
        hs = fmaf(Pc[(size_t)c * NLANE + t], hs, Sc[(size_t)c * NLANE + t]);
    }
}

// Pass 3: replay chunk from H0, C-dot + D*x + *silu(z).
__global__ void k_scan3(const float* __restrict__ DL, const float* __restrict__ XA,
                        const float* __restrict__ XD, const float* __restrict__ SZ,
                        const float* __restrict__ A_log, const float* __restrict__ Dp,
                        const float* __restrict__ H0, float* __restrict__ Y) {
    int b    = blockIdx.x;
    int dblk = blockIdx.y;
    int ch   = blockIdx.z;
    int tid  = threadIdx.x;
    int s    = tid & 15;
    int d    = dblk * 16 + (tid >> 4);
    float A  = -__expf(A_log[d * DSv + s]);
    float Dd = Dp[d];
    int lane = (b * DIv + d) * DSv + s;
    float h  = H0[(size_t)ch * NLANE + lane];
    const size_t posBase = (size_t)b * LSEQ + (size_t)ch * CH;
    for (int l = 0; l < CH; ++l) {
        size_t base = posBase + l;
        float delta = DL[base * DIv + d];
        float x     = XA[base * DIv + d];
        float Bv    = XD[base * 36 + DRv + s];
        float Cv    = XD[base * 36 + DRv + DSv + s];
        float dA    = __expf(delta * A);
        h = fmaf(dA, h, delta * Bv * x);
        float p = h * Cv;
        p += __shfl_xor(p, 1);
        p += __shfl_xor(p, 2);
        p += __shfl_xor(p, 4);
        p += __shfl_xor(p, 8);
        if (s == 0) {
            float y = p + Dd * x;
            Y[base * DIv + d] = y * SZ[base * DIv + d];
        }
    }
}

// ---------------- out = y @ out_w^T ----------------
__global__ void k_out(const float* __restrict__ Y, const float* __restrict__ out_w,
                      float* __restrict__ CF) {
    int idx = blockIdx.x * blockDim.x + threadIdx.x;
    if (idx >= NPOS * DMv) return;
    int e   = idx & 63;
    int pos = idx >> 6;
    const float4* y4 = (const float4*)(Y + (size_t)pos * DIv);
    const float4* w4 = (const float4*)(out_w + (size_t)e * DIv);
    float acc = 0.f;
#pragma unroll
    for (int k = 0; k < DIv / 4; ++k) {
        float4 a = y4[k], b = w4[k];
        acc = fmaf(a.x, b.x, acc); acc = fmaf(a.y, b.y, acc);
        acc = fmaf(a.z, b.z, acc); acc = fmaf(a.w, b.w, acc);
    }
    CF[idx] = acc;
}

// ---------------- residual combine: OUT = relu(0.5*(cf1+cf2) + RES) ----------------
__global__ void k_combine(const float* __restrict__ CF, const float* __restrict__ RES,
                          float* __restrict__ OUT) {
    int idx = blockIdx.x * blockDim.x + threadIdx.x;
    if (idx >= HB * LSEQ * DMv) return;
    float v = 0.5f * (CF[idx] + CF[idx + (size_t)HB * LSEQ * DMv]) + RES[idx];
    OUT[idx] = fmaxf(v, 0.f);
}

// ---------------- build u0 for path a: half-channel swap ----------------
__global__ void k_prep_a(const float* __restrict__ Ms, const float* __restrict__ Pan,
                         float* __restrict__ U) {
    int idx = blockIdx.x * blockDim.x + threadIdx.x;
    if (idx >= NPOS * DMv) return;
    int e   = idx & 63;
    int pos = idx >> 6;
    int c   = pos & 2047;
    int b8  = pos >> 11;
    int b   = b8 & 3;
    bool lower = c < (LSEQ / 2);
    const float* src = (b8 < HB) ? (lower ? Ms : Pan) : (lower ? Pan : Ms);
    U[idx] = src[((size_t)b * LSEQ + c) * DMv + e];
}

// ---------------- build u0 for path b: channel interleave ----------------
__global__ void k_prep_b(const float* __restrict__ Ms, const float* __restrict__ Pan,
                         float* __restrict__ U) {
    int idx = blockIdx.x * blockDim.x + threadIdx.x;
    if (idx >= NPOS * DMv) return;
    int e   = idx & 63;
    int pos = idx >> 6;
    int c   = pos & 2047;
    int b8  = pos >> 11;
    int b   = b8 & 3;
    bool even = (c & 1) == 0;
    const float* src = (b8 < HB) ? (even ? Pan : Ms) : (even ? Ms : Pan);
    U[idx] = src[((size_t)b * LSEQ + c) * DMv + e];
}

extern "C" void kernel_launch(void* const* d_in, const int* in_sizes, int n_in,
                              void* d_out, int out_size, void* d_ws, size_t ws_size,
                              hipStream_t stream) {
    const float* Ms_in  = (const float*)d_in[0];
    const float* Pan_in = (const float*)d_in[1];
    const float* pa[9];
    const float* pb[9];
    for (int i = 0; i < 9; ++i) {
        pa[i] = (const float*)d_in[2 + i];
        pb[i] = (const float*)d_in[11 + i];
    }
    float* out    = (float*)d_out;
    float* OutMs  = out;
    float* OutPan = out + (size_t)HB * LSEQ * DMv;

    float* ws = (float*)d_ws;
    size_t o = 0;
    float* U0 = ws + o; o += (size_t)NPOS * DMv;        // 1M floats
    float* U1 = ws + o; o += (size_t)NPOS * DMv;        // 1M
    float* XR = ws + o; o += (size_t)NPOS * DIv;        // 2M (x_raw, reused as Y)
    float* XA = ws + o; o += (size_t)NPOS * DIv;        // 2M (x after conv+silu)
    float* SZ = ws + o; o += (size_t)NPOS * DIv;        // 2M (silu(z))
    float* XD = ws + o; o += (size_t)NPOS * 36;         // 0.59M (dt|B|C)
    float* DL = ws + o; o += (size_t)NPOS * DIv;        // 2M (delta)
    float* Pc = ws + o; o += (size_t)NCH * NLANE;       // 0.5M
    float* Sc = ws + o; o += (size_t)NCH * NLANE;       // 0.5M
    float* H0 = ws + o; o += (size_t)NCH * NLANE;       // 0.5M

    const int TB = 256;
    auto mamba = [&](const float* u, float* cf, const float* const* P, int layer) {
        const float* in_w   = P[0] + (size_t)layer * 2 * DIv * DMv;
        const float* conv_w = P[1] + (size_t)layer * DIv * KCv;
        const float* conv_b = P[2] + (size_t)layer * DIv;
        const float* xp_w   = P[3] + (size_t)layer * (DRv + 2 * DSv) * DIv;
        const float* dt_w   = P[4] + (size_t)layer * DIv * DRv;
        const float* dt_b   = P[5] + (size_t)layer * DIv;
        const float* A_log  = P[6] + (size_t)layer * DIv * DSv;
        const float* Dp     = P[7] + (size_t)layer * DIv;
        const float* out_w  = P[8] + (size_t)layer * DMv * DIv;

        int n1 = NPOS * 2 * DIv;
        k_xz<<<(n1 + TB - 1) / TB, TB, 0, stream>>>(u, in_w, XR, SZ);
        int n2 = NPOS * DIv;
        k_conv<<<(n2 + TB - 1) / TB, TB, 0, stream>>>(XR, conv_w, conv_b, XA);
        int n3 = NPOS * 36;
        k_xdbl<<<(n3 + TB - 1) / TB, TB, 0, stream>>>(XA, xp_w, XD);
        k_delta<<<(n2 + TB - 1) / TB, TB, 0, stream>>>(XD, dt_w, dt_b, DL);
        dim3 g1(BB, DIv / 16, NCH);
        k_scan1<<<g1, TB, 0, stream>>>(DL, XA, XD, A_log, Pc, Sc);
        k_scan2<<<(NLANE + TB - 1) / TB, TB, 0, stream>>>(Pc, Sc, H0);
        k_scan3<<<g1, TB, 0, stream>>>(DL, XA, XD, SZ, A_log, Dp, H0, XR);
        int n4 = NPOS * DMv;
        k_out<<<(n4 + TB - 1) / TB, TB, 0, stream>>>(XR, out_w, cf);
    };

    int np = NPOS * DMv;
    int nc = HB * LSEQ * DMv;

    // ---- path a (updates Ms) ----
    k_prep_a<<<(np + TB - 1) / TB, TB, 0, stream>>>(Ms_in, Pan_in, U0);
    mamba(U0, U1, pa, 0);
    k_combine<<<(nc + TB - 1) / TB, TB, 0, stream>>>(U1, Ms_in, OutMs);
    mamba(U1, U0, pa, 1);
    k_combine<<<(nc + TB - 1) / TB, TB, 0, stream>>>(U0, OutMs, OutMs);

    // ---- path b (updates Pan) ----
    k_prep_b<<<(np + TB - 1) / TB, TB, 0, stream>>>(OutMs, Pan_in, U0);
    mamba(U0, U1, pb, 0);
    k_combine<<<(nc + TB - 1) / TB, TB, 0, stream>>>(U1, Pan_in, OutPan);
    mamba(U1, U0, pb, 1);
    k_combine<<<(nc + TB - 1) / TB, TB, 0, stream>>>(U0, OutPan, OutPan);
}

// Round 3
// 711.524 us; speedup vs baseline: 8.8924x; 1.9940x over previous
//
#include <hip/hip_runtime.h>
#include <math.h>

// Problem constants
constexpr int BB   = 8;      // mamba batch (2x half-batch)
constexpr int HB   = 4;      // half batch
constexpr int LSEQ = 2048;   // sequence length
constexpr int DMv  = 64;     // d_model
constexpr int DIv  = 128;    // d_inner
constexpr int DSv  = 16;     // d_state
constexpr int DRv  = 4;      // dt rank
constexpr int KCv  = 4;      // conv kernel
constexpr int NPOS = BB * LSEQ;          // 16384 positions
constexpr int CH   = 64;                 // scan chunk length
constexpr int NCH  = LSEQ / CH;          // 32 chunks
constexpr int NLANE = BB * DIv * DSv;    // 16384 scan lanes

#define DEV static __device__ __forceinline__

DEV float siluf(float v) { return v / (1.0f + __expf(-v)); }
DEV float softplusf(float v) { return (v > 20.0f) ? v : log1pf(__expf(v)); }

// ---------------- weight transposes (once per call) ----------------
// dst[z][c*R + r] = src[z][r*C + c];  z in [0,4): {pa L0, pa L1, pb L0, pb L1}
__global__ void k_transpose(const float* __restrict__ Aa, const float* __restrict__ Ab,
                            int R, int C, float* __restrict__ dst) {
    int z = blockIdx.z;
    const float* src = (z < 2) ? (Aa + (size_t)z * R * C) : (Ab + (size_t)(z - 2) * R * C);
    float* d = dst + (size_t)z * R * C;
    int idx = blockIdx.x * blockDim.x + threadIdx.x;
    if (idx >= R * C) return;
    int r = idx / C, c = idx % C;
    d[c * R + r] = src[idx];
}

// ---------------- xz GEMV: weights in regs (coalesced), u rows scalar-broadcast ---
// WT = in_w^T, shape [64][256]. Block 256 threads = 256 output cols e.
// Each block does TPX consecutive positions.
constexpr int TPX = 32;
__global__ __launch_bounds__(256) void k_xz(const float* __restrict__ U,
                                            const float* __restrict__ WT,
                                            float* __restrict__ XR, float* __restrict__ SZ) {
    int e  = threadIdx.x;
    int p0 = blockIdx.x * TPX;
    float w[DMv];
#pragma unroll
    for (int k = 0; k < DMv; ++k) w[k] = WT[k * 256 + e];
    for (int p = 0; p < TPX; p += 4) {
        const float* u0 = U + (size_t)(p0 + p) * DMv;
        float a0 = 0.f, a1 = 0.f, a2 = 0.f, a3 = 0.f;
#pragma unroll
        for (int k = 0; k < DMv; ++k) {
            float wk = w[k];
            a0 = fmaf(u0[k],            wk, a0);
            a1 = fmaf(u0[DMv + k],      wk, a1);
            a2 = fmaf(u0[2 * DMv + k],  wk, a2);
            a3 = fmaf(u0[3 * DMv + k],  wk, a3);
        }
        float acc[4] = {a0, a1, a2, a3};
#pragma unroll
        for (int i = 0; i < 4; ++i) {
            size_t pos = (size_t)(p0 + p + i);
            if (e < DIv) XR[pos * DIv + e] = acc[i];
            else         SZ[pos * DIv + (e - DIv)] = siluf(acc[i]);
        }
    }
}

// ---------------- causal depthwise conv (K=4) + silu ----------------
__global__ void k_conv(const float* __restrict__ XR, const float* __restrict__ conv_w,
                       const float* __restrict__ conv_b, float* __restrict__ XA) {
    int idx = blockIdx.x * blockDim.x + threadIdx.x;
    if (idx >= NPOS * DIv) return;
    int d   = idx & 127;
    int pos = idx >> 7;
    int b   = pos >> 11;
    int l   = pos & 2047;
    float acc = conv_b[d];
#pragma unroll
    for (int k = 0; k < KCv; ++k) {
        int l2 = l - (KCv - 1) + k;
        if (l2 >= 0)
            acc = fmaf(conv_w[d * KCv + k], XR[((size_t)((b << 11) | l2)) * DIv + d], acc);
    }
    XA[idx] = siluf(acc);
}

// ---------------- xdbl = x_act @ xp_w^T via transposed weights ----------------
// WT shape [128][36]
__global__ void k_xdbl(const float* __restrict__ XA, const float* __restrict__ WT,
                       float* __restrict__ XD) {
    int idx = blockIdx.x * blockDim.x + threadIdx.x;
    if (idx >= NPOS * 36) return;
    int e   = idx % 36;
    int pos = idx / 36;
    const float* x = XA + (size_t)pos * DIv;
    float accA = 0.f, accB = 0.f;
#pragma unroll
    for (int k = 0; k < DIv; k += 2) {
        accA = fmaf(x[k],     WT[k * 36 + e],       accA);
        accB = fmaf(x[k + 1], WT[(k + 1) * 36 + e], accB);
    }
    XD[idx] = accA + accB;
}

// ---------------- delta = softplus(dt @ dt_w^T + dt_b) ----------------
__global__ void k_delta(const float* __restrict__ XD, const float* __restrict__ dt_w,
                        const float* __restrict__ dt_b, float* __restrict__ DL) {
    int idx = blockIdx.x * blockDim.x + threadIdx.x;
    if (idx >= NPOS * DIv) return;
    int d   = idx & 127;
    int pos = idx >> 7;
    const float* dt = XD + (size_t)pos * 36;
    float acc = dt_b[d];
#pragma unroll
    for (int r = 0; r < DRv; ++r) acc = fmaf(dt[r], dt_w[d * DRv + r], acc);
    DL[idx] = softplusf(acc);
}

// =========== chunked parallel scan ===========
// Pass 1: per-chunk product of dA and local scan value (h starting from 0).
// grid (BB, DIv/16, NCH), block 256 = 16 d x 16 s
__global__ void k_scan1(const float* __restrict__ DL, const float* __restrict__ XA,
                        const float* __restrict__ XD, const float* __restrict__ A_log,
                        float* __restrict__ Pc, float* __restrict__ Sc) {
    int b    = blockIdx.x;
    int dblk = blockIdx.y;
    int ch   = blockIdx.z;
    int tid  = threadIdx.x;
    int s    = tid & 15;
    int d    = dblk * 16 + (tid >> 4);
    float A  = -__expf(A_log[d * DSv + s]);
    float h  = 0.f, P = 1.f;
    const size_t posBase = (size_t)b * LSEQ + (size_t)ch * CH;
    for (int l = 0; l < CH; ++l) {
        size_t base = posBase + l;
        float delta = DL[base * DIv + d];
        float x     = XA[base * DIv + d];
        float Bv    = XD[base * 36 + DRv + s];
        float dA    = __expf(delta * A);
        h = fmaf(dA, h, delta * Bv * x);
        P *= dA;
    }
    int lane = (b * DIv + d) * DSv + s;
    Pc[(size_t)ch * NLANE + lane] = P;
    Sc[(size_t)ch * NLANE + lane] = h;
}

// Pass 2: serial combine over chunks -> chunk-start states. one thread per lane.
__global__ void k_scan2(const float* __restrict__ Pc, const float* __restrict__ Sc,
                        float* __restrict__ H0) {
    int t = blockIdx.x * blockDim.x + threadIdx.x;
    if (t >= NLANE) return;
    float hs = 0.f;
#pragma unroll
    for (int c = 0; c < NCH; ++c) {
        H0[(size_t)c * NLANE + t] = hs;
        hs = fmaf(Pc[(size_t)c * NLANE + t], hs, Sc[(size_t)c * NLANE + t]);
    }
}

// Pass 3: replay chunk from H0, C-dot + D*x + *silu(z).
__global__ void k_scan3(const float* __restrict__ DL, const float* __restrict__ XA,
                        const float* __restrict__ XD, const float* __restrict__ SZ,
                        const float* __restrict__ A_log, const float* __restrict__ Dp,
                        const float* __restrict__ H0, float* __restrict__ Y) {
    int b    = blockIdx.x;
    int dblk = blockIdx.y;
    int ch   = blockIdx.z;
    int tid  = threadIdx.x;
    int s    = tid & 15;
    int d    = dblk * 16 + (tid >> 4);
    float A  = -__expf(A_log[d * DSv + s]);
    float Dd = Dp[d];
    int lane = (b * DIv + d) * DSv + s;
    float h  = H0[(size_t)ch * NLANE + lane];
    const size_t posBase = (size_t)b * LSEQ + (size_t)ch * CH;
    for (int l = 0; l < CH; ++l) {
        size_t base = posBase + l;
        float delta = DL[base * DIv + d];
        float x     = XA[base * DIv + d];
        float Bv    = XD[base * 36 + DRv + s];
        float Cv    = XD[base * 36 + DRv + DSv + s];
        float dA    = __expf(delta * A);
        h = fmaf(dA, h, delta * Bv * x);
        float p = h * Cv;
        p += __shfl_xor(p, 1);
        p += __shfl_xor(p, 2);
        p += __shfl_xor(p, 4);
        p += __shfl_xor(p, 8);
        if (s == 0) {
            float y = p + Dd * x;
            Y[base * DIv + d] = y * SZ[base * DIv + d];
        }
    }
}

// ---------------- out GEMV: weights in regs via transposed out_w [128][64] --------
constexpr int TPO = 32;
__global__ __launch_bounds__(256) void k_out(const float* __restrict__ Y,
                                             const float* __restrict__ WT,
                                             float* __restrict__ CF) {
    int e  = threadIdx.x & 63;
    int ps = threadIdx.x >> 6;   // 0..3 (wave-uniform)
    int p0 = blockIdx.x * TPO;
    float w[DIv];
#pragma unroll
    for (int k = 0; k < DIv; ++k) w[k] = WT[k * 64 + e];
    for (int p = ps; p < TPO; p += 4) {
        const float* y0 = Y + (size_t)(p0 + p) * DIv;
        float accA = 0.f, accB = 0.f;
#pragma unroll
        for (int k = 0; k < DIv; k += 2) {
            accA = fmaf(y0[k],     w[k],     accA);
            accB = fmaf(y0[k + 1], w[k + 1], accB);
        }
        CF[(size_t)(p0 + p) * DMv + e] = accA + accB;
    }
}

// ---------------- residual combine: OUT = relu(0.5*(cf1+cf2) + RES) ----------------
__global__ void k_combine(const float* __restrict__ CF, const float* __restrict__ RES,
                          float* __restrict__ OUT) {
    int idx = blockIdx.x * blockDim.x + threadIdx.x;
    if (idx >= HB * LSEQ * DMv) return;
    float v = 0.5f * (CF[idx] + CF[idx + (size_t)HB * LSEQ * DMv]) + RES[idx];
    OUT[idx] = fmaxf(v, 0.f);
}

// ---------------- build u0 for path a: half-channel swap ----------------
__global__ void k_prep_a(const float* __restrict__ Ms, const float* __restrict__ Pan,
                         float* __restrict__ U) {
    int idx = blockIdx.x * blockDim.x + threadIdx.x;
    if (idx >= NPOS * DMv) return;
    int e   = idx & 63;
    int pos = idx >> 6;
    int c   = pos & 2047;
    int b8  = pos >> 11;
    int b   = b8 & 3;
    bool lower = c < (LSEQ / 2);
    const float* src = (b8 < HB) ? (lower ? Ms : Pan) : (lower ? Pan : Ms);
    U[idx] = src[((size_t)b * LSEQ + c) * DMv + e];
}

// ---------------- build u0 for path b: channel interleave ----------------
__global__ void k_prep_b(const float* __restrict__ Ms, const float* __restrict__ Pan,
                         float* __restrict__ U) {
    int idx = blockIdx.x * blockDim.x + threadIdx.x;
    if (idx >= NPOS * DMv) return;
    int e   = idx & 63;
    int pos = idx >> 6;
    int c   = pos & 2047;
    int b8  = pos >> 11;
    int b   = b8 & 3;
    bool even = (c & 1) == 0;
    const float* src = (b8 < HB) ? (even ? Pan : Ms) : (even ? Ms : Pan);
    U[idx] = src[((size_t)b * LSEQ + c) * DMv + e];
}

extern "C" void kernel_launch(void* const* d_in, const int* in_sizes, int n_in,
                              void* d_out, int out_size, void* d_ws, size_t ws_size,
                              hipStream_t stream) {
    const float* Ms_in  = (const float*)d_in[0];
    const float* Pan_in = (const float*)d_in[1];
    const float* pa[9];
    const float* pb[9];
    for (int i = 0; i < 9; ++i) {
        pa[i] = (const float*)d_in[2 + i];
        pb[i] = (const float*)d_in[11 + i];
    }
    float* out    = (float*)d_out;
    float* OutMs  = out;
    float* OutPan = out + (size_t)HB * LSEQ * DMv;

    float* ws = (float*)d_ws;
    size_t o = 0;
    float* U0 = ws + o; o += (size_t)NPOS * DMv;        // 1M floats
    float* U1 = ws + o; o += (size_t)NPOS * DMv;        // 1M
    float* XR = ws + o; o += (size_t)NPOS * DIv;        // 2M (x_raw, reused as Y)
    float* XA = ws + o; o += (size_t)NPOS * DIv;        // 2M (x after conv+silu)
    float* SZ = ws + o; o += (size_t)NPOS * DIv;        // 2M (silu(z))
    float* XD = ws + o; o += (size_t)NPOS * 36;         // 0.59M (dt|B|C)
    float* DL = ws + o; o += (size_t)NPOS * DIv;        // 2M (delta)
    float* Pc = ws + o; o += (size_t)NCH * NLANE;       // 0.5M
    float* Sc = ws + o; o += (size_t)NCH * NLANE;       // 0.5M
    float* H0 = ws + o; o += (size_t)NCH * NLANE;       // 0.5M
    float* W2T  = ws + o; o += (size_t)4 * DMv * 2 * DIv;   // in_w^T  per (path,layer): [64][256]
    float* XPWT = ws + o; o += (size_t)4 * DIv * 36;        // xp_w^T: [128][36]
    float* OUTWT= ws + o; o += (size_t)4 * DIv * DMv;       // out_w^T: [128][64]

    const int TB = 256;

    // ---- one-time weight transposes (z = path*2 + layer) ----
    {
        dim3 gt1((2 * DIv * DMv + TB - 1) / TB, 1, 4);
        k_transpose<<<gt1, TB, 0, stream>>>(pa[0], pb[0], 2 * DIv, DMv, W2T);
        dim3 gt2((36 * DIv + TB - 1) / TB, 1, 4);
        k_transpose<<<gt2, TB, 0, stream>>>(pa[3], pb[3], 36, DIv, XPWT);
        dim3 gt3((DMv * DIv + TB - 1) / TB, 1, 4);
        k_transpose<<<gt3, TB, 0, stream>>>(pa[8], pb[8], DMv, DIv, OUTWT);
    }

    auto mamba = [&](const float* u, float* cf, const float* const* P, int z, int layer) {
        const float* conv_w = P[1] + (size_t)layer * DIv * KCv;
        const float* conv_b = P[2] + (size_t)layer * DIv;
        const float* dt_w   = P[4] + (size_t)layer * DIv * DRv;
        const float* dt_b   = P[5] + (size_t)layer * DIv;
        const float* A_log  = P[6] + (size_t)layer * DIv * DSv;
        const float* Dp     = P[7] + (size_t)layer * DIv;
        const float* wxzT   = W2T   + (size_t)z * DMv * 2 * DIv;
        const float* wxpT   = XPWT  + (size_t)z * DIv * 36;
        const float* woutT  = OUTWT + (size_t)z * DIv * DMv;

        k_xz<<<NPOS / TPX, 256, 0, stream>>>(u, wxzT, XR, SZ);
        int n2 = NPOS * DIv;
        k_conv<<<(n2 + TB - 1) / TB, TB, 0, stream>>>(XR, conv_w, conv_b, XA);
        int n3 = NPOS * 36;
        k_xdbl<<<(n3 + TB - 1) / TB, TB, 0, stream>>>(XA, wxpT, XD);
        k_delta<<<(n2 + TB - 1) / TB, TB, 0, stream>>>(XD, dt_w, dt_b, DL);
        dim3 g1(BB, DIv / 16, NCH);
        k_scan1<<<g1, TB, 0, stream>>>(DL, XA, XD, A_log, Pc, Sc);
        k_scan2<<<(NLANE + TB - 1) / TB, TB, 0, stream>>>(Pc, Sc, H0);
        k_scan3<<<g1, TB, 0, stream>>>(DL, XA, XD, SZ, A_log, Dp, H0, XR);
        k_out<<<NPOS / TPO, 256, 0, stream>>>(XR, woutT, cf);
    };

    int np = NPOS * DMv;
    int nc = HB * LSEQ * DMv;

    // ---- path a (updates Ms); z = 0,1 ----
    k_prep_a<<<(np + TB - 1) / TB, TB, 0, stream>>>(Ms_in, Pan_in, U0);
    mamba(U0, U1, pa, 0, 0);
    k_combine<<<(nc + TB - 1) / TB, TB, 0, stream>>>(U1, Ms_in, OutMs);
    mamba(U1, U0, pa, 1, 1);
    k_combine<<<(nc + TB - 1) / TB, TB, 0, stream>>>(U0, OutMs, OutMs);

    // ---- path b (updates Pan); z = 2,3 ----
    k_prep_b<<<(np + TB - 1) / TB, TB, 0, stream>>>(OutMs, Pan_in, U0);
    mamba(U0, U1, pb, 2, 0);
    k_combine<<<(nc + TB - 1) / TB, TB, 0, stream>>>(U1, Pan_in, OutPan);
    mamba(U1, U0, pb, 3, 1);
    k_combine<<<(nc + TB - 1) / TB, TB, 0, stream>>>(U0, OutPan, OutPan);
}

// Round 4
// 693.747 us; speedup vs baseline: 9.1203x; 1.0256x over previous
//
#include <hip/hip_runtime.h>
#include <math.h>

// Problem constants
constexpr int BB   = 8;      // mamba batch (2x half-batch)
constexpr int HB   = 4;      // half batch
constexpr int LSEQ = 2048;   // sequence length
constexpr int DMv  = 64;     // d_model
constexpr int DIv  = 128;    // d_inner
constexpr int DSv  = 16;     // d_state
constexpr int DRv  = 4;      // dt rank
constexpr int KCv  = 4;      // conv kernel
constexpr int NPOS = BB * LSEQ;          // 16384 positions
constexpr int CH   = 32;                 // scan chunk length
constexpr int NCH  = LSEQ / CH;          // 64 chunks
constexpr int NLANE = BB * DIv * DSv;    // 16384 scan lanes

#define DEV static __device__ __forceinline__

DEV float siluf(float v) { return v / (1.0f + __expf(-v)); }
DEV float softplusf(float v) { return (v > 20.0f) ? v : log1pf(__expf(v)); }

// ---------------- weight transposes (once per call) ----------------
__global__ void k_transpose(const float* __restrict__ Aa, const float* __restrict__ Ab,
                            int R, int C, float* __restrict__ dst) {
    int z = blockIdx.z;
    const float* src = (z < 2) ? (Aa + (size_t)z * R * C) : (Ab + (size_t)(z - 2) * R * C);
    float* d = dst + (size_t)z * R * C;
    int idx = blockIdx.x * blockDim.x + threadIdx.x;
    if (idx >= R * C) return;
    int r = idx / C, c = idx % C;
    d[c * R + r] = src[idx];
}

// ---------------- xz GEMV with fused input gather ----------------
// MODE 0: plain rows from S1. MODE 1: prep_a gather. MODE 2: prep_b gather.
constexpr int TPX = 32;
template<int MODE>
__global__ __launch_bounds__(256) void k_xz(const float* __restrict__ S1,
                                            const float* __restrict__ S2,
                                            const float* __restrict__ WT,
                                            float* __restrict__ XR, float* __restrict__ SZ) {
    int e  = threadIdx.x;
    int p0 = blockIdx.x * TPX;
    float w[DMv];
#pragma unroll
    for (int k = 0; k < DMv; ++k) w[k] = WT[k * 256 + e];
    for (int p = 0; p < TPX; p += 4) {
        const float* rows[4];
#pragma unroll
        for (int i = 0; i < 4; ++i) {
            int pos = p0 + p + i;
            if (MODE == 0) {
                rows[i] = S1 + (size_t)pos * DMv;
            } else {
                int c  = pos & 2047;
                int b8 = pos >> 11;
                int b  = b8 & 3;
                bool first = (MODE == 1) ? (c < (LSEQ / 2)) : ((c & 1) == 0);
                const float* sel;
                if (MODE == 1) sel = (b8 < HB) ? (first ? S1 : S2) : (first ? S2 : S1);
                else           sel = (b8 < HB) ? (first ? S2 : S1) : (first ? S1 : S2);
                rows[i] = sel + ((size_t)b * LSEQ + c) * DMv;
            }
        }
        float a0 = 0.f, a1 = 0.f, a2 = 0.f, a3 = 0.f;
#pragma unroll
        for (int k = 0; k < DMv; ++k) {
            float wk = w[k];
            a0 = fmaf(rows[0][k], wk, a0);
            a1 = fmaf(rows[1][k], wk, a1);
            a2 = fmaf(rows[2][k], wk, a2);
            a3 = fmaf(rows[3][k], wk, a3);
        }
        float acc[4] = {a0, a1, a2, a3};
#pragma unroll
        for (int i = 0; i < 4; ++i) {
            size_t pos = (size_t)(p0 + p + i);
            if (e < DIv) XR[pos * DIv + e] = acc[i];
            else         SZ[pos * DIv + (e - DIv)] = siluf(acc[i]);
        }
    }
}

// ---------------- causal depthwise conv (K=4) + silu ----------------
__global__ void k_conv(const float* __restrict__ XR, const float* __restrict__ conv_w,
                       const float* __restrict__ conv_b, float* __restrict__ XA) {
    int idx = blockIdx.x * blockDim.x + threadIdx.x;
    if (idx >= NPOS * DIv) return;
    int d   = idx & 127;
    int pos = idx >> 7;
    int b   = pos >> 11;
    int l   = pos & 2047;
    float acc = conv_b[d];
#pragma unroll
    for (int k = 0; k < KCv; ++k) {
        int l2 = l - (KCv - 1) + k;
        if (l2 >= 0)
            acc = fmaf(conv_w[d * KCv + k], XR[((size_t)((b << 11) | l2)) * DIv + d], acc);
    }
    XA[idx] = siluf(acc);
}

// ---------------- xdbl = x_act @ xp_w^T via transposed weights [128][36] ---------
__global__ void k_xdbl(const float* __restrict__ XA, const float* __restrict__ WT,
                       float* __restrict__ XD) {
    int idx = blockIdx.x * blockDim.x + threadIdx.x;
    if (idx >= NPOS * 36) return;
    int e   = idx % 36;
    int pos = idx / 36;
    const float* x = XA + (size_t)pos * DIv;
    float accA = 0.f, accB = 0.f;
#pragma unroll
    for (int k = 0; k < DIv; k += 2) {
        accA = fmaf(x[k],     WT[k * 36 + e],       accA);
        accB = fmaf(x[k + 1], WT[(k + 1) * 36 + e], accB);
    }
    XD[idx] = accA + accB;
}

// =========== chunked parallel scan, s-in-registers ===========
// thread = (b, d, chunk): 16 h-states in regs; delta recomputed from XD on the fly.
// grid (BB, NCH), block 128 (= d).
__global__ __launch_bounds__(128) void k_scan1(const float* __restrict__ XA,
                                               const float* __restrict__ XD,
                                               const float* __restrict__ A_log,
                                               const float* __restrict__ dt_w,
                                               const float* __restrict__ dt_b,
                                               float* __restrict__ Pc, float* __restrict__ Sc) {
    int d  = threadIdx.x;
    int b  = blockIdx.x;
    int ch = blockIdx.y;
    float A[DSv];
#pragma unroll
    for (int s = 0; s < DSv; ++s) A[s] = -__expf(A_log[d * DSv + s]);
    float w0 = dt_w[d * DRv], w1 = dt_w[d * DRv + 1], w2 = dt_w[d * DRv + 2], w3 = dt_w[d * DRv + 3];
    float bb = dt_b[d];
    float h[DSv], P[DSv];
#pragma unroll
    for (int s = 0; s < DSv; ++s) { h[s] = 0.f; P[s] = 1.f; }
    const size_t posBase = (size_t)b * LSEQ + (size_t)ch * CH;
#pragma unroll 2
    for (int l = 0; l < CH; ++l) {
        size_t base = posBase + l;
        const float* xd = XD + base * 36;
        float delta = softplusf(fmaf(xd[0], w0, fmaf(xd[1], w1, fmaf(xd[2], w2, fmaf(xd[3], w3, bb)))));
        float x  = XA[base * DIv + d];
        float dx = delta * x;
#pragma unroll
        for (int s = 0; s < DSv; ++s) {
            float dA = __expf(delta * A[s]);
            h[s] = fmaf(dA, h[s], dx * xd[DRv + s]);
            P[s] *= dA;
        }
    }
    size_t ofs = (size_t)ch * NLANE + (size_t)(b * DIv + d) * DSv;
    float4* p4 = (float4*)(Pc + ofs);
    float4* s4 = (float4*)(Sc + ofs);
#pragma unroll
    for (int q = 0; q < 4; ++q) {
        p4[q] = make_float4(P[4 * q], P[4 * q + 1], P[4 * q + 2], P[4 * q + 3]);
        s4[q] = make_float4(h[4 * q], h[4 * q + 1], h[4 * q + 2], h[4 * q + 3]);
    }
}

// Pass 2: serial combine over chunks -> chunk-start states. one thread per lane.
__global__ void k_scan2(const float* __restrict__ Pc, const float* __restrict__ Sc,
                        float* __restrict__ H0) {
    int t = blockIdx.x * blockDim.x + threadIdx.x;
    if (t >= NLANE) return;
    float hs = 0.f;
    for (int c = 0; c < NCH; ++c) {
        H0[(size_t)c * NLANE + t] = hs;
        hs = fmaf(Pc[(size_t)c * NLANE + t], hs, Sc[(size_t)c * NLANE + t]);
    }
}

// Pass 3: replay chunk from H0 with C-dot + D*x + *silu(z), all in-register.
__global__ __launch_bounds__(128) void k_scan3(const float* __restrict__ XA,
                                               const float* __restrict__ XD,
                                               const float* __restrict__ SZ,
                                               const float* __restrict__ A_log,
                                               const float* __restrict__ dt_w,
                                               const float* __restrict__ dt_b,
                                               const float* __restrict__ Dp,
                                               const float* __restrict__ H0,
                                               float* __restrict__ Y) {
    int d  = threadIdx.x;
    int b  = blockIdx.x;
    int ch = blockIdx.y;
    float A[DSv];
#pragma unroll
    for (int s = 0; s < DSv; ++s) A[s] = -__expf(A_log[d * DSv + s]);
    float w0 = dt_w[d * DRv], w1 = dt_w[d * DRv + 1], w2 = dt_w[d * DRv + 2], w3 = dt_w[d * DRv + 3];
    float bb = dt_b[d];
    float Dd = Dp[d];
    float h[DSv];
    size_t ofs = (size_t)ch * NLANE + (size_t)(b * DIv + d) * DSv;
    const float4* h4 = (const float4*)(H0 + ofs);
#pragma unroll
    for (int q = 0; q < 4; ++q) {
        float4 v = h4[q];
        h[4 * q] = v.x; h[4 * q + 1] = v.y; h[4 * q + 2] = v.z; h[4 * q + 3] = v.w;
    }
    const size_t posBase = (size_t)b * LSEQ + (size_t)ch * CH;
#pragma unroll 2
    for (int l = 0; l < CH; ++l) {
        size_t base = posBase + l;
        const float* xd = XD + base * 36;
        float delta = softplusf(fmaf(xd[0], w0, fmaf(xd[1], w1, fmaf(xd[2], w2, fmaf(xd[3], w3, bb)))));
        float x  = XA[base * DIv + d];
        float dx = delta * x;
        float p = 0.f;
#pragma unroll
        for (int s = 0; s < DSv; ++s) {
            float dA = __expf(delta * A[s]);
            h[s] = fmaf(dA, h[s], dx * xd[DRv + s]);
            p = fmaf(h[s], xd[DRv + DSv + s], p);
        }
        float y = fmaf(Dd, x, p);
        Y[base * DIv + d] = y * SZ[base * DIv + d];
    }
}

// ---------------- fused out-proj + residual combine ----------------
// computes cf for both batch halves; OUT = relu(0.5*(cf1+cf2)+RES); optionally stores CF.
constexpr int TPO = 32;
template<bool SAVE_CF>
__global__ __launch_bounds__(256) void k_outc(const float* __restrict__ Y,
                                              const float* __restrict__ WT,
                                              const float* __restrict__ RES,
                                              float* __restrict__ CF,
                                              float* __restrict__ OUT) {
    int e  = threadIdx.x & 63;
    int ps = threadIdx.x >> 6;   // 0..3 (wave-uniform)
    int p0 = blockIdx.x * TPO;
    float w[DIv];
#pragma unroll
    for (int k = 0; k < DIv; ++k) w[k] = WT[k * 64 + e];
    for (int p = ps; p < TPO; p += 4) {
        size_t pos1 = (size_t)(p0 + p);
        size_t pos2 = pos1 + (size_t)HB * LSEQ;
        const float* y1 = Y + pos1 * DIv;
        const float* y2 = Y + pos2 * DIv;
        float a1 = 0.f, b1 = 0.f, a2 = 0.f, b2 = 0.f;
#pragma unroll
        for (int k = 0; k < DIv; k += 2) {
            a1 = fmaf(y1[k],     w[k],     a1);
            b1 = fmaf(y1[k + 1], w[k + 1], b1);
            a2 = fmaf(y2[k],     w[k],     a2);
            b2 = fmaf(y2[k + 1], w[k + 1], b2);
        }
        float c1 = a1 + b1, c2 = a2 + b2;
        if (SAVE_CF) {
            CF[pos1 * DMv + e] = c1;
            CF[pos2 * DMv + e] = c2;
        }
        float v = fmaf(0.5f, c1 + c2, RES[pos1 * DMv + e]);
        OUT[pos1 * DMv + e] = fmaxf(v, 0.f);
    }
}

extern "C" void kernel_launch(void* const* d_in, const int* in_sizes, int n_in,
                              void* d_out, int out_size, void* d_ws, size_t ws_size,
                              hipStream_t stream) {
    const float* Ms_in  = (const float*)d_in[0];
    const float* Pan_in = (const float*)d_in[1];
    const float* pa[9];
    const float* pb[9];
    for (int i = 0; i < 9; ++i) {
        pa[i] = (const float*)d_in[2 + i];
        pb[i] = (const float*)d_in[11 + i];
    }
    float* out    = (float*)d_out;
    float* OutMs  = out;
    float* OutPan = out + (size_t)HB * LSEQ * DMv;

    float* ws = (float*)d_ws;
    size_t o = 0;
    float* CF = ws + o; o += (size_t)NPOS * DMv;        // 1M floats (raw mamba out)
    float* XR = ws + o; o += (size_t)NPOS * DIv;        // 2M (x_raw, reused as Y)
    float* XA = ws + o; o += (size_t)NPOS * DIv;        // 2M (x after conv+silu)
    float* SZ = ws + o; o += (size_t)NPOS * DIv;        // 2M (silu(z))
    float* XD = ws + o; o += (size_t)NPOS * 36;         // 0.59M (dt|B|C)
    float* Pc = ws + o; o += (size_t)NCH * NLANE;       // 1M
    float* Sc = ws + o; o += (size_t)NCH * NLANE;       // 1M
    float* H0 = ws + o; o += (size_t)NCH * NLANE;       // 1M
    float* W2T  = ws + o; o += (size_t)4 * DMv * 2 * DIv;   // in_w^T : [64][256]
    float* XPWT = ws + o; o += (size_t)4 * DIv * 36;        // xp_w^T : [128][36]
    float* OUTWT= ws + o; o += (size_t)4 * DIv * DMv;       // out_w^T: [128][64]

    const int TB = 256;

    // ---- one-time weight transposes (z = path*2 + layer) ----
    {
        dim3 gt1((2 * DIv * DMv + TB - 1) / TB, 1, 4);
        k_transpose<<<gt1, TB, 0, stream>>>(pa[0], pb[0], 2 * DIv, DMv, W2T);
        dim3 gt2((36 * DIv + TB - 1) / TB, 1, 4);
        k_transpose<<<gt2, TB, 0, stream>>>(pa[3], pb[3], 36, DIv, XPWT);
        dim3 gt3((DMv * DIv + TB - 1) / TB, 1, 4);
        k_transpose<<<gt3, TB, 0, stream>>>(pa[8], pb[8], DMv, DIv, OUTWT);
    }

    // body of one mamba after k_xz has filled XR/SZ
    auto mamba_core = [&](const float* const* P, int z, int layer) {
        const float* conv_w = P[1] + (size_t)layer * DIv * KCv;
        const float* conv_b = P[2] + (size_t)layer * DIv;
        const float* dt_w   = P[4] + (size_t)layer * DIv * DRv;
        const float* dt_b   = P[5] + (size_t)layer * DIv;
        const float* A_log  = P[6] + (size_t)layer * DIv * DSv;
        const float* wxpT   = XPWT + (size_t)z * DIv * 36;

        int n2 = NPOS * DIv;
        k_conv<<<(n2 + TB - 1) / TB, TB, 0, stream>>>(XR, conv_w, conv_b, XA);
        int n3 = NPOS * 36;
        k_xdbl<<<(n3 + TB - 1) / TB, TB, 0, stream>>>(XA, wxpT, XD);
        dim3 g1(BB, NCH);
        k_scan1<<<g1, 128, 0, stream>>>(XA, XD, A_log, dt_w, dt_b, Pc, Sc);
        k_scan2<<<(NLANE + TB - 1) / TB, TB, 0, stream>>>(Pc, Sc, H0);
        k_scan3<<<g1, 128, 0, stream>>>(XA, XD, SZ, A_log, dt_w, dt_b,
                                        P[7] + (size_t)layer * DIv, H0, XR);
    };

    int nOutBlocks = (HB * LSEQ) / TPO;

    // ---- path a (updates Ms); z = 0,1 ----
    k_xz<1><<<NPOS / TPX, 256, 0, stream>>>(Ms_in, Pan_in, W2T + (size_t)0 * DMv * 2 * DIv, XR, SZ);
    mamba_core(pa, 0, 0);
    k_outc<true><<<nOutBlocks, 256, 0, stream>>>(XR, OUTWT + (size_t)0 * DIv * DMv, Ms_in, CF, OutMs);
    k_xz<0><<<NPOS / TPX, 256, 0, stream>>>(CF, nullptr, W2T + (size_t)1 * DMv * 2 * DIv, XR, SZ);
    mamba_core(pa, 1, 1);
    k_outc<false><<<nOutBlocks, 256, 0, stream>>>(XR, OUTWT + (size_t)1 * DIv * DMv, OutMs, nullptr, OutMs);

    // ---- path b (updates Pan); z = 2,3 ----
    k_xz<2><<<NPOS / TPX, 256, 0, stream>>>(OutMs, Pan_in, W2T + (size_t)2 * DMv * 2 * DIv, XR, SZ);
    mamba_core(pb, 2, 0);
    k_outc<true><<<nOutBlocks, 256, 0, stream>>>(XR, OUTWT + (size_t)2 * DIv * DMv, Pan_in, CF, OutPan);
    k_xz<0><<<NPOS / TPX, 256, 0, stream>>>(CF, nullptr, W2T + (size_t)3 * DMv * 2 * DIv, XR, SZ);
    mamba_core(pb, 3, 1);
    k_outc<false><<<nOutBlocks, 256, 0, stream>>>(XR, OUTWT + (size_t)3 * DIv * DMv, OutPan, nullptr, OutPan);
}

// Round 5
// 577.106 us; speedup vs baseline: 10.9636x; 1.2021x over previous
//
#include <hip/hip_runtime.h>
#include <math.h>

// Problem constants
constexpr int BB   = 8;      // mamba batch (2x half-batch)
constexpr int HB   = 4;      // half batch
constexpr int LSEQ = 2048;   // sequence length
constexpr int DMv  = 64;     // d_model
constexpr int DIv  = 128;    // d_inner
constexpr int DSv  = 16;     // d_state
constexpr int DRv  = 4;      // dt rank
constexpr int KCv  = 4;      // conv kernel
constexpr int NPOS = BB * LSEQ;          // 16384 positions
constexpr int CH   = 16;                 // scan chunk length
constexpr int NCH  = LSEQ / CH;          // 128 chunks
constexpr int NLANE = BB * DIv * DSv;    // 16384 scan lanes

#define DEV static __device__ __forceinline__

DEV float siluf(float v) { return v / (1.0f + __expf(-v)); }
DEV float softplusf(float v) { return (v > 20.0f) ? v : log1pf(__expf(v)); }

// ---------------- weight repack (once per call) ----------------
// plain transpose: dst[c*R + r] = src[r*C + c]
__global__ void k_transpose(const float* __restrict__ Aa, const float* __restrict__ Ab,
                            int R, int C, float* __restrict__ dst) {
    int z = blockIdx.z;
    const float* src = (z < 2) ? (Aa + (size_t)z * R * C) : (Ab + (size_t)(z - 2) * R * C);
    float* d = dst + (size_t)z * R * C;
    int idx = blockIdx.x * blockDim.x + threadIdx.x;
    if (idx >= R * C) return;
    int r = idx / C, c = idx % C;
    d[c * R + r] = src[idx];
}

// quad-pack: src[e*K + k] -> dst[((k>>2)*E + e)*4 + (k&3)]
// thread e then loads float4 q at f4[q*E + e]: lanes stride 16B = coalesced.
__global__ void k_quadpack(const float* __restrict__ Aa, const float* __restrict__ Ab,
                           int E, int K, float* __restrict__ dst) {
    int z = blockIdx.z;
    const float* src = (z < 2) ? (Aa + (size_t)z * E * K) : (Ab + (size_t)(z - 2) * E * K);
    float* d = dst + (size_t)z * E * K;
    int idx = blockIdx.x * blockDim.x + threadIdx.x;
    if (idx >= E * K) return;
    int e = idx / K, k = idx % K;
    d[((size_t)(k >> 2) * E + e) * 4 + (k & 3)] = src[idx];
}

// ---------------- xz GEMV with fused input gather ----------------
// MODE 0: plain rows from S1. MODE 1: prep_a gather. MODE 2: prep_b gather.
constexpr int TPX = 8;
template<int MODE>
__global__ __launch_bounds__(256) void k_xz(const float* __restrict__ S1,
                                            const float* __restrict__ S2,
                                            const float* __restrict__ WQ,
                                            float* __restrict__ XR, float* __restrict__ SZ) {
    int e  = threadIdx.x;
    int p0 = blockIdx.x * TPX;
    const float4* wq4 = (const float4*)WQ;   // [K/4=16][E=256] float4
    float w[DMv];
#pragma unroll
    for (int q = 0; q < DMv / 4; ++q) {
        float4 v = wq4[q * 256 + e];
        w[4 * q] = v.x; w[4 * q + 1] = v.y; w[4 * q + 2] = v.z; w[4 * q + 3] = v.w;
    }
    for (int p = 0; p < TPX; p += 4) {
        const float* rows[4];
#pragma unroll
        for (int i = 0; i < 4; ++i) {
            int pos = p0 + p + i;
            if (MODE == 0) {
                rows[i] = S1 + (size_t)pos * DMv;
            } else {
                int c  = pos & 2047;
                int b8 = pos >> 11;
                int b  = b8 & 3;
                bool first = (MODE == 1) ? (c < (LSEQ / 2)) : ((c & 1) == 0);
                const float* sel;
                if (MODE == 1) sel = (b8 < HB) ? (first ? S1 : S2) : (first ? S2 : S1);
                else           sel = (b8 < HB) ? (first ? S2 : S1) : (first ? S1 : S2);
                rows[i] = sel + ((size_t)b * LSEQ + c) * DMv;
            }
        }
        float a0 = 0.f, a1 = 0.f, a2 = 0.f, a3 = 0.f;
#pragma unroll
        for (int k = 0; k < DMv; ++k) {
            float wk = w[k];
            a0 = fmaf(rows[0][k], wk, a0);
            a1 = fmaf(rows[1][k], wk, a1);
            a2 = fmaf(rows[2][k], wk, a2);
            a3 = fmaf(rows[3][k], wk, a3);
        }
        float acc[4] = {a0, a1, a2, a3};
#pragma unroll
        for (int i = 0; i < 4; ++i) {
            size_t pos = (size_t)(p0 + p + i);
            if (e < DIv) XR[pos * DIv + e] = acc[i];
            else         SZ[pos * DIv + (e - DIv)] = siluf(acc[i]);
        }
    }
}

// ---------------- causal depthwise conv (K=4) + silu ----------------
__global__ void k_conv(const float* __restrict__ XR, const float* __restrict__ conv_w,
                       const float* __restrict__ conv_b, float* __restrict__ XA) {
    int idx = blockIdx.x * blockDim.x + threadIdx.x;
    if (idx >= NPOS * DIv) return;
    int d   = idx & 127;
    int pos = idx >> 7;
    int b   = pos >> 11;
    int l   = pos & 2047;
    float acc = conv_b[d];
#pragma unroll
    for (int k = 0; k < KCv; ++k) {
        int l2 = l - (KCv - 1) + k;
        if (l2 >= 0)
            acc = fmaf(conv_w[d * KCv + k], XR[((size_t)((b << 11) | l2)) * DIv + d], acc);
    }
    XA[idx] = siluf(acc);
}

// ---------------- xdbl = x_act @ xp_w^T via transposed weights [128][36] ---------
__global__ void k_xdbl(const float* __restrict__ XA, const float* __restrict__ WT,
                       float* __restrict__ XD) {
    int idx = blockIdx.x * blockDim.x + threadIdx.x;
    if (idx >= NPOS * 36) return;
    int e   = idx % 36;
    int pos = idx / 36;
    const float* x = XA + (size_t)pos * DIv;
    float accA = 0.f, accB = 0.f;
#pragma unroll
    for (int k = 0; k < DIv; k += 2) {
        accA = fmaf(x[k],     WT[k * 36 + e],       accA);
        accB = fmaf(x[k + 1], WT[(k + 1) * 36 + e], accB);
    }
    XD[idx] = accA + accB;
}

// =========== chunked parallel scan, s-in-registers ===========
// thread = (b, d, chunk): 16 h-states in regs; delta recomputed from XD on the fly.
// grid (BB, NCH), block 128 (= d).
__global__ __launch_bounds__(128) void k_scan1(const float* __restrict__ XA,
                                               const float* __restrict__ XD,
                                               const float* __restrict__ A_log,
                                               const float* __restrict__ dt_w,
                                               const float* __restrict__ dt_b,
                                               float* __restrict__ Pc, float* __restrict__ Sc) {
    int d  = threadIdx.x;
    int b  = blockIdx.x;
    int ch = blockIdx.y;
    float A[DSv];
#pragma unroll
    for (int s = 0; s < DSv; ++s) A[s] = -__expf(A_log[d * DSv + s]);
    float w0 = dt_w[d * DRv], w1 = dt_w[d * DRv + 1], w2 = dt_w[d * DRv + 2], w3 = dt_w[d * DRv + 3];
    float bb = dt_b[d];
    float h[DSv], P[DSv];
#pragma unroll
    for (int s = 0; s < DSv; ++s) { h[s] = 0.f; P[s] = 1.f; }
    const size_t posBase = (size_t)b * LSEQ + (size_t)ch * CH;
#pragma unroll 2
    for (int l = 0; l < CH; ++l) {
        size_t base = posBase + l;
        const float* xd = XD + base * 36;
        float delta = softplusf(fmaf(xd[0], w0, fmaf(xd[1], w1, fmaf(xd[2], w2, fmaf(xd[3], w3, bb)))));
        float x  = XA[base * DIv + d];
        float dx = delta * x;
#pragma unroll
        for (int s = 0; s < DSv; ++s) {
            float dA = __expf(delta * A[s]);
            h[s] = fmaf(dA, h[s], dx * xd[DRv + s]);
            P[s] *= dA;
        }
    }
    size_t ofs = (size_t)ch * NLANE + (size_t)(b * DIv + d) * DSv;
    float4* p4 = (float4*)(Pc + ofs);
    float4* s4 = (float4*)(Sc + ofs);
#pragma unroll
    for (int q = 0; q < 4; ++q) {
        p4[q] = make_float4(P[4 * q], P[4 * q + 1], P[4 * q + 2], P[4 * q + 3]);
        s4[q] = make_float4(h[4 * q], h[4 * q + 1], h[4 * q + 2], h[4 * q + 3]);
    }
}

// Pass 2: serial combine over chunks -> chunk-start states, IN PLACE over Pc.
// PcH0[c] is read (P of chunk c) then overwritten with the start state of chunk c.
__global__ void k_scan2(float* PcH0, const float* __restrict__ Sc) {
    int t = blockIdx.x * blockDim.x + threadIdx.x;
    if (t >= NLANE) return;
    float hs = 0.f;
    for (int c = 0; c < NCH; ++c) {
        size_t ix = (size_t)c * NLANE + t;
        float p = PcH0[ix];
        float s = Sc[ix];
        PcH0[ix] = hs;
        hs = fmaf(p, hs, s);
    }
}

// Pass 3: replay chunk from H0 (=Pc) with C-dot + D*x + *silu(z), in-register.
__global__ __launch_bounds__(128) void k_scan3(const float* __restrict__ XA,
                                               const float* __restrict__ XD,
                                               const float* __restrict__ SZ,
                                               const float* __restrict__ A_log,
                                               const float* __restrict__ dt_w,
                                               const float* __restrict__ dt_b,
                                               const float* __restrict__ Dp,
                                               const float* __restrict__ H0,
                                               float* __restrict__ Y) {
    int d  = threadIdx.x;
    int b  = blockIdx.x;
    int ch = blockIdx.y;
    float A[DSv];
#pragma unroll
    for (int s = 0; s < DSv; ++s) A[s] = -__expf(A_log[d * DSv + s]);
    float w0 = dt_w[d * DRv], w1 = dt_w[d * DRv + 1], w2 = dt_w[d * DRv + 2], w3 = dt_w[d * DRv + 3];
    float bb = dt_b[d];
    float Dd = Dp[d];
    float h[DSv];
    size_t ofs = (size_t)ch * NLANE + (size_t)(b * DIv + d) * DSv;
    const float4* h4 = (const float4*)(H0 + ofs);
#pragma unroll
    for (int q = 0; q < 4; ++q) {
        float4 v = h4[q];
        h[4 * q] = v.x; h[4 * q + 1] = v.y; h[4 * q + 2] = v.z; h[4 * q + 3] = v.w;
    }
    const size_t posBase = (size_t)b * LSEQ + (size_t)ch * CH;
#pragma unroll 2
    for (int l = 0; l < CH; ++l) {
        size_t base = posBase + l;
        const float* xd = XD + base * 36;
        float delta = softplusf(fmaf(xd[0], w0, fmaf(xd[1], w1, fmaf(xd[2], w2, fmaf(xd[3], w3, bb)))));
        float x  = XA[base * DIv + d];
        float dx = delta * x;
        float p = 0.f;
#pragma unroll
        for (int s = 0; s < DSv; ++s) {
            float dA = __expf(delta * A[s]);
            h[s] = fmaf(dA, h[s], dx * xd[DRv + s]);
            p = fmaf(h[s], xd[DRv + DSv + s], p);
        }
        float y = fmaf(Dd, x, p);
        Y[base * DIv + d] = y * SZ[base * DIv + d];
    }
}

// ---------------- fused out-proj + residual combine ----------------
// computes cf for both batch halves; OUT = relu(0.5*(cf1+cf2)+RES); optionally stores CF.
constexpr int TPO = 8;
template<bool SAVE_CF>
__global__ __launch_bounds__(256) void k_outc(const float* __restrict__ Y,
                                              const float* __restrict__ WQ,
                                              const float* __restrict__ RES,
                                              float* __restrict__ CF,
                                              float* __restrict__ OUT) {
    int e  = threadIdx.x & 63;
    int ps = threadIdx.x >> 6;   // 0..3 (wave-uniform)
    int p0 = blockIdx.x * TPO;
    const float4* wq4 = (const float4*)WQ;   // [K/4=32][E=64] float4
    float w[DIv];
#pragma unroll
    for (int q = 0; q < DIv / 4; ++q) {
        float4 v = wq4[q * 64 + e];
        w[4 * q] = v.x; w[4 * q + 1] = v.y; w[4 * q + 2] = v.z; w[4 * q + 3] = v.w;
    }
    for (int p = ps; p < TPO; p += 4) {
        size_t pos1 = (size_t)(p0 + p);
        size_t pos2 = pos1 + (size_t)HB * LSEQ;
        const float* y1 = Y + pos1 * DIv;
        const float* y2 = Y + pos2 * DIv;
        float a1 = 0.f, b1 = 0.f, a2 = 0.f, b2 = 0.f;
#pragma unroll
        for (int k = 0; k < DIv; k += 2) {
            a1 = fmaf(y1[k],     w[k],     a1);
            b1 = fmaf(y1[k + 1], w[k + 1], b1);
            a2 = fmaf(y2[k],     w[k],     a2);
            b2 = fmaf(y2[k + 1], w[k + 1], b2);
        }
        float c1 = a1 + b1, c2 = a2 + b2;
        if (SAVE_CF) {
            CF[pos1 * DMv + e] = c1;
            CF[pos2 * DMv + e] = c2;
        }
        float v = fmaf(0.5f, c1 + c2, RES[pos1 * DMv + e]);
        OUT[pos1 * DMv + e] = fmaxf(v, 0.f);
    }
}

extern "C" void kernel_launch(void* const* d_in, const int* in_sizes, int n_in,
                              void* d_out, int out_size, void* d_ws, size_t ws_size,
                              hipStream_t stream) {
    const float* Ms_in  = (const float*)d_in[0];
    const float* Pan_in = (const float*)d_in[1];
    const float* pa[9];
    const float* pb[9];
    for (int i = 0; i < 9; ++i) {
        pa[i] = (const float*)d_in[2 + i];
        pb[i] = (const float*)d_in[11 + i];
    }
    float* out    = (float*)d_out;
    float* OutMs  = out;
    float* OutPan = out + (size_t)HB * LSEQ * DMv;

    float* ws = (float*)d_ws;
    size_t o = 0;
    float* CF = ws + o; o += (size_t)NPOS * DMv;        // 1M floats (raw mamba out)
    float* XR = ws + o; o += (size_t)NPOS * DIv;        // 2M (x_raw, reused as Y)
    float* XA = ws + o; o += (size_t)NPOS * DIv;        // 2M (x after conv+silu)
    float* SZ = ws + o; o += (size_t)NPOS * DIv;        // 2M (silu(z))
    float* XD = ws + o; o += (size_t)NPOS * 36;         // 0.59M (dt|B|C)
    float* Pc = ws + o; o += (size_t)NCH * NLANE;       // 2M  (later aliased as H0)
    float* Sc = ws + o; o += (size_t)NCH * NLANE;       // 2M
    float* W2Q  = ws + o; o += (size_t)4 * DMv * 2 * DIv;   // in_w quad-packed
    float* XPWT = ws + o; o += (size_t)4 * DIv * 36;        // xp_w^T : [128][36]
    float* OUTQ = ws + o; o += (size_t)4 * DIv * DMv;       // out_w quad-packed

    const int TB = 256;

    // ---- one-time weight repacks (z = path*2 + layer) ----
    {
        dim3 gt1((2 * DIv * DMv + TB - 1) / TB, 1, 4);
        k_quadpack<<<gt1, TB, 0, stream>>>(pa[0], pb[0], 2 * DIv, DMv, W2Q);
        dim3 gt2((36 * DIv + TB - 1) / TB, 1, 4);
        k_transpose<<<gt2, TB, 0, stream>>>(pa[3], pb[3], 36, DIv, XPWT);
        dim3 gt3((DMv * DIv + TB - 1) / TB, 1, 4);
        k_quadpack<<<gt3, TB, 0, stream>>>(pa[8], pb[8], DMv, DIv, OUTQ);
    }

    // body of one mamba after k_xz has filled XR/SZ
    auto mamba_core = [&](const float* const* P, int z, int layer) {
        const float* conv_w = P[1] + (size_t)layer * DIv * KCv;
        const float* conv_b = P[2] + (size_t)layer * DIv;
        const float* dt_w   = P[4] + (size_t)layer * DIv * DRv;
        const float* dt_b   = P[5] + (size_t)layer * DIv;
        const float* A_log  = P[6] + (size_t)layer * DIv * DSv;
        const float* wxpT   = XPWT + (size_t)z * DIv * 36;

        int n2 = NPOS * DIv;
        k_conv<<<(n2 + TB - 1) / TB, TB, 0, stream>>>(XR, conv_w, conv_b, XA);
        int n3 = NPOS * 36;
        k_xdbl<<<(n3 + TB - 1) / TB, TB, 0, stream>>>(XA, wxpT, XD);
        dim3 g1(BB, NCH);
        k_scan1<<<g1, 128, 0, stream>>>(XA, XD, A_log, dt_w, dt_b, Pc, Sc);
        k_scan2<<<(NLANE + TB - 1) / TB, TB, 0, stream>>>(Pc, Sc);
        k_scan3<<<g1, 128, 0, stream>>>(XA, XD, SZ, A_log, dt_w, dt_b,
                                        P[7] + (size_t)layer * DIv, Pc, XR);
    };

    int nOutBlocks = (HB * LSEQ) / TPO;

    // ---- path a (updates Ms); z = 0,1 ----
    k_xz<1><<<NPOS / TPX, 256, 0, stream>>>(Ms_in, Pan_in, W2Q + (size_t)0 * DMv * 2 * DIv, XR, SZ);
    mamba_core(pa, 0, 0);
    k_outc<true><<<nOutBlocks, 256, 0, stream>>>(XR, OUTQ + (size_t)0 * DIv * DMv, Ms_in, CF, OutMs);
    k_xz<0><<<NPOS / TPX, 256, 0, stream>>>(CF, nullptr, W2Q + (size_t)1 * DMv * 2 * DIv, XR, SZ);
    mamba_core(pa, 1, 1);
    k_outc<false><<<nOutBlocks, 256, 0, stream>>>(XR, OUTQ + (size_t)1 * DIv * DMv, OutMs, nullptr, OutMs);

    // ---- path b (updates Pan); z = 2,3 ----
    k_xz<2><<<NPOS / TPX, 256, 0, stream>>>(OutMs, Pan_in, W2Q + (size_t)2 * DMv * 2 * DIv, XR, SZ);
    mamba_core(pb, 2, 0);
    k_outc<true><<<nOutBlocks, 256, 0, stream>>>(XR, OUTQ + (size_t)2 * DIv * DMv, Pan_in, CF, OutPan);
    k_xz<0><<<NPOS / TPX, 256, 0, stream>>>(CF, nullptr, W2Q + (size_t)3 * DMv * 2 * DIv, XR, SZ);
    mamba_core(pb, 3, 1);
    k_outc<false><<<nOutBlocks, 256, 0, stream>>>(XR, OUTQ + (size_t)3 * DIv * DMv, OutPan, nullptr, OutPan);
}

// Round 6
// 388.697 us; speedup vs baseline: 16.2778x; 1.4847x over previous
//
#include <hip/hip_runtime.h>
#include <math.h>

// Problem constants
constexpr int BB   = 8;      // mamba batch (2x half-batch)
constexpr int HB   = 4;      // half batch
constexpr int LSEQ = 2048;   // sequence length
constexpr int DMv  = 64;     // d_model
constexpr int DIv  = 128;    // d_inner
constexpr int DSv  = 16;     // d_state
constexpr int DRv  = 4;      // dt rank
constexpr int KCv  = 4;      // conv kernel
constexpr int NPOS = BB * LSEQ;          // 16384 positions
constexpr int CH   = 16;                 // scan chunk length
constexpr int NCH  = LSEQ / CH;          // 128 chunks
constexpr int NLANE = BB * DIv * DSv;    // 16384 scan lanes

#define DEV static __device__ __forceinline__

DEV float siluf(float v) { return v / (1.0f + __expf(-v)); }
DEV float softplusf(float v) { return (v > 20.0f) ? v : log1pf(__expf(v)); }

// ---------------- weight repack (once per call) ----------------
// plain transpose: dst[c*R + r] = src[r*C + c]
__global__ void k_transpose(const float* __restrict__ Aa, const float* __restrict__ Ab,
                            int R, int C, float* __restrict__ dst) {
    int z = blockIdx.z;
    const float* src = (z < 2) ? (Aa + (size_t)z * R * C) : (Ab + (size_t)(z - 2) * R * C);
    float* d = dst + (size_t)z * R * C;
    int idx = blockIdx.x * blockDim.x + threadIdx.x;
    if (idx >= R * C) return;
    int r = idx / C, c = idx % C;
    d[c * R + r] = src[idx];
}

// quad-pack: src[e*K + k] -> dst[((k>>2)*E + e)*4 + (k&3)]
__global__ void k_quadpack(const float* __restrict__ Aa, const float* __restrict__ Ab,
                           int E, int K, float* __restrict__ dst) {
    int z = blockIdx.z;
    const float* src = (z < 2) ? (Aa + (size_t)z * E * K) : (Ab + (size_t)(z - 2) * E * K);
    float* d = dst + (size_t)z * E * K;
    int idx = blockIdx.x * blockDim.x + threadIdx.x;
    if (idx >= E * K) return;
    int e = idx / K, k = idx % K;
    d[((size_t)(k >> 2) * E + e) * 4 + (k & 3)] = src[idx];
}

// ================= fused front: in-proj(+gather) + conv + x-proj + scan pass 1 ====
// grid (BB, NCH), block 256. Chunk of CH=16 positions per block.
// MODE 0: rows from S1. MODE 1: prep_a gather. MODE 2: prep_b gather.
template<int MODE>
__global__ __launch_bounds__(256) void k_front(
    const float* __restrict__ S1, const float* __restrict__ S2,
    const float* __restrict__ WQ,          // in_w quad-packed [16][256]xfloat4
    const float* __restrict__ conv_w, const float* __restrict__ conv_b,
    const float* __restrict__ XPWT,        // xp_w^T [128][36]
    const float* __restrict__ A_log, const float* __restrict__ dt_w,
    const float* __restrict__ dt_b,
    float* __restrict__ XA_g, float* __restrict__ SZ_g, float* __restrict__ XD_g,
    float* __restrict__ Pc, float* __restrict__ Sc)
{
    __shared__ float lds_x[(CH + 3) * DIv];   // raw x rows incl. 3-halo
    __shared__ float lds_xa[CH * DIv];        // conv+silu output
    __shared__ float lds_xd[CH * 36];         // dt|B|C
    __shared__ float lds_w[DIv * 36];         // xp_w^T staged
    const int t  = threadIdx.x;
    const int b8 = blockIdx.x, ch = blockIdx.y;
    const int c0 = ch * CH;

    // stage xp_w^T into LDS (coalesced)
    for (int f = t; f < DIv * 36; f += 256) lds_w[f] = XPWT[f];

    // in-proj weight column in regs (coalesced quad loads)
    float w[DMv];
    {
        const float4* wq4 = (const float4*)WQ;
#pragma unroll
        for (int q = 0; q < DMv / 4; ++q) {
            float4 v = wq4[q * 256 + t];
            w[4 * q] = v.x; w[4 * q + 1] = v.y; w[4 * q + 2] = v.z; w[4 * q + 3] = v.w;
        }
    }

    // ---- phase 1: xz GEMV over CH+3 rows (3-row halo for conv) ----
    for (int i = 0; i < CH + 3; ++i) {
        int c = c0 - 3 + i;
        float acc = 0.f;
        if (c >= 0) {
            const float* row;
            if (MODE == 0) {
                row = S1 + ((size_t)b8 * LSEQ + c) * DMv;
            } else {
                int b = b8 & 3;
                bool first = (MODE == 1) ? (c < (LSEQ / 2)) : ((c & 1) == 0);
                const float* sel;
                if (MODE == 1) sel = (b8 < HB) ? (first ? S1 : S2) : (first ? S2 : S1);
                else           sel = (b8 < HB) ? (first ? S2 : S1) : (first ? S1 : S2);
                row = sel + ((size_t)b * LSEQ + c) * DMv;
            }
            const float4* r4 = (const float4*)row;
#pragma unroll
            for (int q = 0; q < DMv / 4; ++q) {
                float4 v = r4[q];
                acc = fmaf(v.x, w[4 * q],     acc);
                acc = fmaf(v.y, w[4 * q + 1], acc);
                acc = fmaf(v.z, w[4 * q + 2], acc);
                acc = fmaf(v.w, w[4 * q + 3], acc);
            }
        }
        if (t < DIv) lds_x[i * DIv + t] = acc;
        else if (i >= 3) SZ_g[((size_t)b8 * LSEQ + c) * DIv + (t - DIv)] = siluf(acc);
    }
    __syncthreads();

    // ---- phase 2: causal conv (K=4) + silu ----
    for (int f = t; f < CH * DIv; f += 256) {
        int l = f >> 7, d = f & 127;
        float acc = conv_b[d];
#pragma unroll
        for (int k = 0; k < KCv; ++k)
            acc = fmaf(conv_w[d * KCv + k], lds_x[(l + k) * DIv + d], acc);
        float xa = siluf(acc);
        lds_xa[f] = xa;
        XA_g[((size_t)b8 * LSEQ + c0) * DIv + f] = xa;
    }
    __syncthreads();

    // ---- phase 3: x-proj (36 outputs per position) ----
    for (int f = t; f < CH * 36; f += 256) {
        int l = f / 36, e = f % 36;
        const float* xa = lds_xa + l * DIv;
        float a0 = 0.f, a1 = 0.f;
#pragma unroll
        for (int k = 0; k < DIv; k += 2) {
            a0 = fmaf(xa[k],     lds_w[k * 36 + e],       a0);
            a1 = fmaf(xa[k + 1], lds_w[(k + 1) * 36 + e], a1);
        }
        float v = a0 + a1;
        lds_xd[f] = v;
        XD_g[((size_t)b8 * LSEQ + c0) * 36 + f] = v;
    }
    __syncthreads();

    // ---- phase 4: scan pass 1 (thread = (d, s-half), 8 states in regs) ----
    {
        int d = t & 127, sh = t >> 7;
        float A[8], h[8], P[8];
#pragma unroll
        for (int s = 0; s < 8; ++s) {
            A[s] = -__expf(A_log[d * DSv + sh * 8 + s]);
            h[s] = 0.f; P[s] = 1.f;
        }
        float w0 = dt_w[d * DRv], w1 = dt_w[d * DRv + 1],
              w2 = dt_w[d * DRv + 2], w3 = dt_w[d * DRv + 3];
        float bb = dt_b[d];
        for (int l = 0; l < CH; ++l) {
            const float* xd = lds_xd + l * 36;
            float delta = softplusf(fmaf(xd[0], w0, fmaf(xd[1], w1, fmaf(xd[2], w2, fmaf(xd[3], w3, bb)))));
            float dx = delta * lds_xa[l * DIv + d];
#pragma unroll
            for (int s = 0; s < 8; ++s) {
                float dA = __expf(delta * A[s]);
                h[s] = fmaf(dA, h[s], dx * xd[DRv + sh * 8 + s]);
                P[s] *= dA;
            }
        }
        size_t ofs = (size_t)ch * NLANE + ((size_t)b8 * DIv + d) * DSv + sh * 8;
        float4* p4 = (float4*)(Pc + ofs);
        float4* s4 = (float4*)(Sc + ofs);
        p4[0] = make_float4(P[0], P[1], P[2], P[3]);
        p4[1] = make_float4(P[4], P[5], P[6], P[7]);
        s4[0] = make_float4(h[0], h[1], h[2], h[3]);
        s4[1] = make_float4(h[4], h[5], h[6], h[7]);
    }
}

// Pass 2: serial combine over chunks -> chunk-start states, IN PLACE over Pc.
__global__ void k_scan2(float* PcH0, const float* __restrict__ Sc) {
    int t = blockIdx.x * blockDim.x + threadIdx.x;
    if (t >= NLANE) return;
    float hs = 0.f;
    for (int c = 0; c < NCH; ++c) {
        size_t ix = (size_t)c * NLANE + t;
        float p = PcH0[ix];
        float s = Sc[ix];
        PcH0[ix] = hs;
        hs = fmaf(p, hs, s);
    }
}

// ================= fused back: scan replay + gate + out-proj + residual =========
// grid (HB, NCH), block 256 = two batch halves x 128 d.
template<bool SAVE_CF>
__global__ __launch_bounds__(256) void k_back(
    const float* __restrict__ XA, const float* __restrict__ XD,
    const float* __restrict__ SZ,
    const float* __restrict__ A_log, const float* __restrict__ dt_w,
    const float* __restrict__ dt_b, const float* __restrict__ Dp,
    const float* __restrict__ H0,          // = Pc after k_scan2
    const float* __restrict__ WQ,          // out_w quad-packed [32][64]xfloat4
    const float* __restrict__ RES,
    float* __restrict__ CF, float* __restrict__ OUT)
{
    __shared__ float lds_xd[2 * CH * 36];
    __shared__ float lds_y[2 * CH * DIv];
    const int t  = threadIdx.x;
    const int bq = blockIdx.x, ch = blockIdx.y;

    // stage XD tiles for both batch halves
    for (int f = t; f < 2 * CH * 36; f += 256) {
        int half = f / (CH * 36), r = f % (CH * 36);
        int beff = bq + half * HB;
        lds_xd[f] = XD[((size_t)beff * LSEQ + ch * CH) * 36 + r];
    }
    __syncthreads();

    // ---- scan replay + C-dot + D*x + silu(z) gate ----
    {
        int half = t >> 7, d = t & 127;
        int beff = bq + half * HB;
        float A[DSv];
#pragma unroll
        for (int s = 0; s < DSv; ++s) A[s] = -__expf(A_log[d * DSv + s]);
        float w0 = dt_w[d * DRv], w1 = dt_w[d * DRv + 1],
              w2 = dt_w[d * DRv + 2], w3 = dt_w[d * DRv + 3];
        float bb = dt_b[d];
        float Dd = Dp[d];
        float h[DSv];
        size_t ofs = (size_t)ch * NLANE + ((size_t)beff * DIv + d) * DSv;
        const float4* h4 = (const float4*)(H0 + ofs);
#pragma unroll
        for (int q = 0; q < 4; ++q) {
            float4 v = h4[q];
            h[4 * q] = v.x; h[4 * q + 1] = v.y; h[4 * q + 2] = v.z; h[4 * q + 3] = v.w;
        }
        const float* xdh = lds_xd + half * CH * 36;
        for (int l = 0; l < CH; ++l) {
            const float* xd = xdh + l * 36;
            float delta = softplusf(fmaf(xd[0], w0, fmaf(xd[1], w1, fmaf(xd[2], w2, fmaf(xd[3], w3, bb)))));
            size_t base = (size_t)beff * LSEQ + ch * CH + l;
            float x  = XA[base * DIv + d];
            float dx = delta * x;
            float p = 0.f;
#pragma unroll
            for (int s = 0; s < DSv; ++s) {
                float dA = __expf(delta * A[s]);
                h[s] = fmaf(dA, h[s], dx * xd[DRv + s]);
                p = fmaf(h[s], xd[DRv + DSv + s], p);
            }
            float y = fmaf(Dd, x, p);
            lds_y[half * CH * DIv + l * DIv + d] = y * SZ[base * DIv + d];
        }
    }
    __syncthreads();

    // ---- out-proj + 0.5*(cf1+cf2)+res, relu ----
    {
        int e = t & 63, grp = t >> 6;
        float w[DIv];
        const float4* wq4 = (const float4*)WQ;
#pragma unroll
        for (int q = 0; q < DIv / 4; ++q) {
            float4 v = wq4[q * 64 + e];
            w[4 * q] = v.x; w[4 * q + 1] = v.y; w[4 * q + 2] = v.z; w[4 * q + 3] = v.w;
        }
#pragma unroll
        for (int i = 0; i < 4; ++i) {
            int l = grp * 4 + i;
            const float* y1 = lds_y + l * DIv;
            const float* y2 = lds_y + CH * DIv + l * DIv;
            float a1 = 0.f, b1 = 0.f, a2 = 0.f, b2 = 0.f;
#pragma unroll
            for (int k = 0; k < DIv; k += 2) {
                a1 = fmaf(y1[k],     w[k],     a1);
                b1 = fmaf(y1[k + 1], w[k + 1], b1);
                a2 = fmaf(y2[k],     w[k],     a2);
                b2 = fmaf(y2[k + 1], w[k + 1], b2);
            }
            float c1 = a1 + b1, c2 = a2 + b2;
            size_t pos1 = (size_t)bq * LSEQ + ch * CH + l;
            size_t pos2 = pos1 + (size_t)HB * LSEQ;
            if (SAVE_CF) {
                CF[pos1 * DMv + e] = c1;
                CF[pos2 * DMv + e] = c2;
            }
            float v = fmaf(0.5f, c1 + c2, RES[pos1 * DMv + e]);
            OUT[pos1 * DMv + e] = fmaxf(v, 0.f);
        }
    }
}

extern "C" void kernel_launch(void* const* d_in, const int* in_sizes, int n_in,
                              void* d_out, int out_size, void* d_ws, size_t ws_size,
                              hipStream_t stream) {
    const float* Ms_in  = (const float*)d_in[0];
    const float* Pan_in = (const float*)d_in[1];
    const float* pa[9];
    const float* pb[9];
    for (int i = 0; i < 9; ++i) {
        pa[i] = (const float*)d_in[2 + i];
        pb[i] = (const float*)d_in[11 + i];
    }
    float* out    = (float*)d_out;
    float* OutMs  = out;
    float* OutPan = out + (size_t)HB * LSEQ * DMv;

    float* ws = (float*)d_ws;
    size_t o = 0;
    float* CF = ws + o; o += (size_t)NPOS * DMv;        // raw mamba out (layer0)
    float* XA = ws + o; o += (size_t)NPOS * DIv;        // conv+silu x
    float* SZ = ws + o; o += (size_t)NPOS * DIv;        // silu(z)
    float* XD = ws + o; o += (size_t)NPOS * 36;         // dt|B|C
    float* Pc = ws + o; o += (size_t)NCH * NLANE;       // chunk products -> H0
    float* Sc = ws + o; o += (size_t)NCH * NLANE;       // chunk local scans
    float* W2Q  = ws + o; o += (size_t)4 * DMv * 2 * DIv;   // in_w quad-packed
    float* XPWT = ws + o; o += (size_t)4 * DIv * 36;        // xp_w^T
    float* OUTQ = ws + o; o += (size_t)4 * DIv * DMv;       // out_w quad-packed

    const int TB = 256;

    // ---- one-time weight repacks (z = path*2 + layer) ----
    {
        dim3 gt1((2 * DIv * DMv + TB - 1) / TB, 1, 4);
        k_quadpack<<<gt1, TB, 0, stream>>>(pa[0], pb[0], 2 * DIv, DMv, W2Q);
        dim3 gt2((36 * DIv + TB - 1) / TB, 1, 4);
        k_transpose<<<gt2, TB, 0, stream>>>(pa[3], pb[3], 36, DIv, XPWT);
        dim3 gt3((DMv * DIv + TB - 1) / TB, 1, 4);
        k_quadpack<<<gt3, TB, 0, stream>>>(pa[8], pb[8], DMv, DIv, OUTQ);
    }

    dim3 gF(BB, NCH);
    dim3 gB(HB, NCH);
    int gS = (NLANE + TB - 1) / TB;

    auto scan_mid = [&]() { k_scan2<<<gS, TB, 0, stream>>>(Pc, Sc); };

    // per-(path,layer) parameter helpers
    auto cw  = [&](const float* const* P, int L) { return P[1] + (size_t)L * DIv * KCv; };
    auto cb  = [&](const float* const* P, int L) { return P[2] + (size_t)L * DIv; };
    auto dw  = [&](const float* const* P, int L) { return P[4] + (size_t)L * DIv * DRv; };
    auto db  = [&](const float* const* P, int L) { return P[5] + (size_t)L * DIv; };
    auto al  = [&](const float* const* P, int L) { return P[6] + (size_t)L * DIv * DSv; };
    auto dp  = [&](const float* const* P, int L) { return P[7] + (size_t)L * DIv; };

    // ---- path a (updates Ms); z = 0,1 ----
    k_front<1><<<gF, 256, 0, stream>>>(Ms_in, Pan_in, W2Q + (size_t)0 * DMv * 2 * DIv,
                                       cw(pa,0), cb(pa,0), XPWT + (size_t)0 * DIv * 36,
                                       al(pa,0), dw(pa,0), db(pa,0), XA, SZ, XD, Pc, Sc);
    scan_mid();
    k_back<true><<<gB, 256, 0, stream>>>(XA, XD, SZ, al(pa,0), dw(pa,0), db(pa,0), dp(pa,0),
                                         Pc, OUTQ + (size_t)0 * DIv * DMv, Ms_in, CF, OutMs);

    k_front<0><<<gF, 256, 0, stream>>>(CF, nullptr, W2Q + (size_t)1 * DMv * 2 * DIv,
                                       cw(pa,1), cb(pa,1), XPWT + (size_t)1 * DIv * 36,
                                       al(pa,1), dw(pa,1), db(pa,1), XA, SZ, XD, Pc, Sc);
    scan_mid();
    k_back<false><<<gB, 256, 0, stream>>>(XA, XD, SZ, al(pa,1), dw(pa,1), db(pa,1), dp(pa,1),
                                          Pc, OUTQ + (size_t)1 * DIv * DMv, OutMs, nullptr, OutMs);

    // ---- path b (updates Pan); z = 2,3 ----
    k_front<2><<<gF, 256, 0, stream>>>(OutMs, Pan_in, W2Q + (size_t)2 * DMv * 2 * DIv,
                                       cw(pb,0), cb(pb,0), XPWT + (size_t)2 * DIv * 36,
                                       al(pb,0), dw(pb,0), db(pb,0), XA, SZ, XD, Pc, Sc);
    scan_mid();
    k_back<true><<<gB, 256, 0, stream>>>(XA, XD, SZ, al(pb,0), dw(pb,0), db(pb,0), dp(pb,0),
                                         Pc, OUTQ + (size_t)2 * DIv * DMv, Pan_in, CF, OutPan);

    k_front<0><<<gF, 256, 0, stream>>>(CF, nullptr, W2Q + (size_t)3 * DMv * 2 * DIv,
                                       cw(pb,1), cb(pb,1), XPWT + (size_t)3 * DIv * 36,
                                       al(pb,1), dw(pb,1), db(pb,1), XA, SZ, XD, Pc, Sc);
    scan_mid();
    k_back<false><<<gB, 256, 0, stream>>>(XA, XD, SZ, al(pb,1), dw(pb,1), db(pb,1), dp(pb,1),
                                          Pc, OUTQ + (size_t)3 * DIv * DMv, OutPan, nullptr, OutPan);
}